// Round 1
// baseline (2477.280 us; speedup 1.0000x reference)
//
#include <hip/hip_runtime.h>
#include <math.h>

namespace {

constexpr int B = 4, N = 128, FIN = 16, F = 64, H = 4, K = 50, C = 256;
constexpr int BN = B * N;
constexpr float EPS = 1e-5f;

__device__ __forceinline__ float silu_f(float x) { return x / (1.0f + __expf(-x)); }
__device__ __forceinline__ float tanh_f(float x) { return 1.0f - 2.0f / (__expf(2.0f * x) + 1.0f); }

__global__ void k_init(const float* __restrict__ x, const float* __restrict__ v,
                       float* __restrict__ xw, float* __restrict__ vw, float* __restrict__ sld) {
  int t = blockIdx.x * blockDim.x + threadIdx.x;
  if (t < B * N * 3) { xw[t] = x[t]; vw[t] = v[t]; }
  if (t < B) sld[t] = 0.0f;
}

__global__ __launch_bounds__(F) void k_embed(const float* __restrict__ hin,
    const float* __restrict__ w1, const float* __restrict__ b1,
    const float* __restrict__ w2, const float* __restrict__ b2, float* __restrict__ h0) {
  int node = blockIdx.x, f = threadIdx.x;
  __shared__ float t1[F];
  float acc = b1[f];
  #pragma unroll
  for (int r = 0; r < FIN; ++r) acc += hin[node * FIN + r] * w1[r * F + f];
  t1[f] = silu_f(acc);
  __syncthreads();
  float acc2 = b2[f];
  #pragma unroll
  for (int r = 0; r < F; ++r) acc2 += t1[r] * w2[r * F + f];
  h0[node * F + f] = acc2;
}

// Per-node precomputation at flow start: hkA/hkB (edge_in halves), e1A/e1B (eo1 halves).
// Also copies h0 into the working h buffer.
__global__ __launch_bounds__(256) void k_pre(const float* __restrict__ h0, float* __restrict__ hw,
    const float* __restrict__ ein_w, const float* __restrict__ eo1w,
    float* __restrict__ hkA, float* __restrict__ hkB,
    float* __restrict__ e1A, float* __restrict__ e1B) {
  int node = blockIdx.x, t = threadIdx.x;
  __shared__ float s_h[F];
  if (t < F) s_h[t] = h0[node * F + t];
  __syncthreads();
  if (t < F) hw[node * F + t] = s_h[t];
  if (t < 228) {
    float acc = 0.f;
    if (t < 50) { int k = t;
      #pragma unroll 16
      for (int r = 0; r < F; ++r) acc += s_h[r] * ein_w[r * K + k];
      hkA[node * K + k] = acc;
    } else if (t < 100) { int k = t - 50;
      #pragma unroll 16
      for (int r = 0; r < F; ++r) acc += s_h[r] * ein_w[(F + r) * K + k];
      hkB[node * K + k] = acc;
    } else if (t < 164) { int c = t - 100;
      #pragma unroll 16
      for (int r = 0; r < F; ++r) acc += s_h[r] * eo1w[r * F + c];
      e1A[node * F + c] = acc;
    } else { int c = t - 164;
      #pragma unroll 16
      for (int r = 0; r < F; ++r) acc += s_h[r] * eo1w[(F + r) * F + c];
      e1B[node * F + c] = acc;
    }
  }
}

// Fused message-passing step for one (b,i), 512 threads / 8 waves.
// Edge MLP phase-split (t1 -> LDS -> he) so <=64 weight regs live at a time (no spills).
// Coeff / h_e / attention split 2-way over j across the doubled thread count.
template<int PRE, int TAIL>
__global__ __launch_bounds__(512, 4) void k_mp(
    float* __restrict__ hw, const float* __restrict__ xp,
    const float* __restrict__ hkA_in, const float* __restrict__ hkB_in,
    const float* __restrict__ e1A_in, const float* __restrict__ e1B_in,
    const float* __restrict__ ein_b, const float* __restrict__ rbf_m, const float* __restrict__ rbf_b,
    const float* __restrict__ eo1w, const float* __restrict__ eo1b,
    const float* __restrict__ eo2w, const float* __restrict__ eo2b,
    const float* __restrict__ xmix,
    const float* __restrict__ p1w, const float* __restrict__ p1b,
    const float* __restrict__ p2w, const float* __restrict__ p2b,
    const float* __restrict__ semw, const float* __restrict__ semb,
    const float* __restrict__ n1w, const float* __restrict__ n1b,
    const float* __restrict__ n2w, const float* __restrict__ n2b,
    const float* __restrict__ ein_w,
    float* __restrict__ hkA_out, float* __restrict__ hkB_out,
    float* __restrict__ e1A_out, float* __restrict__ e1B_out,
    const float* __restrict__ c1w, const float* __restrict__ v1w, const float* __restrict__ v1b,
    const float* __restrict__ v2w,
    float* __restrict__ uA, float* __restrict__ uB, float* __restrict__ mbuf) {
  int blk = blockIdx.x, b = blk >> 7, i = blk & 127;
  int t = threadIdx.x, w = t >> 6, lane = t & 63;
  int bN = b * N;
  constexpr float invN = 1.0f / (float)N;

  __shared__ __align__(16) float s_pool[128 * 68];   // he[j][68]
  __shared__ __align__(16) float s_ovl[4096];        // overlay region (16 KB)
  __shared__ __align__(16) float4 s_dxn[N];          // (dx0,dx1,dx2,dn) per j
  __shared__ float s_inv[N];                         // 1/(dn+EPS)
  __shared__ float s_xpos[N * 3];
  __shared__ float s_hi[F];
  __shared__ float s_zkbase[K];
  __shared__ float s_e1base[F];
  __shared__ __align__(16) float s_zk[8 * 56];
  __shared__ float s_semw[F * H];

  // overlay: t1buf (edge phases) vs post-edge scratch
  float* t1buf   = s_ovl;          // [64][64]
  float* s_cpart = s_ovl;          // [2][256][3]
  float* s_hcin  = s_ovl + 1536;   // [256]
  float* s_hEp   = s_ovl + 1792;   // [2][256]
  float* s_att   = s_ovl + 2304;   // [128][4]
  float* s_part  = s_ovl + 2816;   // [8][64]
  float* s_vec   = s_ovl + 3328;   // [64]
  float* s_cat   = s_ovl + 3392;   // [384]
  float* s_hnew  = s_ovl + 3776;   // [64]
  float* s_wred  = s_ovl + 3840;   // [8]
  float* s_wsum  = s_ovl + 3848;   // [8]

  // ---- staging ----
  for (int idx = t; idx < N * 3; idx += 512) s_xpos[idx] = xp[bN * 3 + idx];
  if (t < 256) s_semw[t] = semw[t];
  else if (t < 320) s_hi[t - 256] = hw[(bN + i) * F + (t - 256)];
  else if (t < 370) s_zkbase[t - 320] = hkA_in[(bN + i) * K + (t - 320)] + ein_b[t - 320];
  else if (t >= 384 && t < 448) s_e1base[t - 384] = e1A_in[(bN + i) * F + (t - 384)] + eo1b[t - 384];
  if (lane >= 50 && lane < 56) s_zk[w * 56 + lane] = 0.f;  // float4 pad
  __syncthreads();
  if (t < N) {
    float dx0 = s_xpos[i * 3 + 0] - s_xpos[t * 3 + 0];
    float dx1 = s_xpos[i * 3 + 1] - s_xpos[t * 3 + 1];
    float dx2 = s_xpos[i * 3 + 2] - s_xpos[t * 3 + 2];
    float dn = sqrtf(dx0 * dx0 + dx1 * dx1 + dx2 * dx2 + EPS * EPS);
    s_dxn[t] = make_float4(dx0, dx1, dx2, dn);
    s_inv[t] = 1.0f / (dn + EPS);
  }
  __syncthreads();

  float rbm = 0.f, rbb = 0.f;
  if (lane < K) { rbm = rbf_m[lane]; rbb = rbf_b[lane]; }

  // ---- edge phases: per j-half, A: z -> t1 (wk live), B: t1 -> he (eo2 live) ----
  for (int half = 0; half < 2; ++half) {
    {  // phase A
      float wk[52];
      #pragma unroll
      for (int k = 0; k < 50; ++k) wk[k] = eo1w[(128 + k) * F + lane];
      wk[50] = 0.f; wk[51] = 0.f;
      float w1d = eo1w[178 * F + lane];
      int jb = half * 64 + w;
      float nhk = (lane < K) ? hkB_in[(bN + jb) * K + lane] : 0.f;
      float ne1 = e1B_in[(bN + jb) * F + lane];
      for (int jj = 0; jj < 8; ++jj) {
        int j = half * 64 + w + 8 * jj;
        float hk = nhk, e1v = ne1;
        if (jj < 7) {
          int jn = j + 8;
          nhk = (lane < K) ? hkB_in[(bN + jn) * K + lane] : 0.f;
          ne1 = e1B_in[(bN + jn) * F + lane];
        }
        float dn = s_dxn[j].w;
        if (lane < K) {
          float hkf = s_zkbase[lane] + hk;
          float e = __expf(-dn) - rbm;
          s_zk[w * 56 + lane] = __expf(-rbb * e * e) * hkf;
        }
        float acc = s_e1base[lane] + e1v + dn * w1d;
        const float4* z4 = (const float4*)(&s_zk[w * 56]);
        #pragma unroll
        for (int k4 = 0; k4 < 13; ++k4) {
          float4 z = z4[k4];
          acc += z.x * wk[4 * k4] + z.y * wk[4 * k4 + 1] + z.z * wk[4 * k4 + 2] + z.w * wk[4 * k4 + 3];
        }
        t1buf[(j & 63) * F + lane] = silu_f(acc);
      }
    }
    __syncthreads();
    {  // phase B
      float er[64];
      #pragma unroll
      for (int r = 0; r < F; ++r) er[r] = eo2w[r * F + lane];
      float b2 = eo2b[lane];
      for (int jj = 0; jj < 8; ++jj) {
        int j = half * 64 + w + 8 * jj;
        float acc = b2;
        const float4* t4 = (const float4*)(&t1buf[(j & 63) * F]);
        #pragma unroll
        for (int r4 = 0; r4 < 16; ++r4) {
          float4 tt = t4[r4];
          acc += tt.x * er[4 * r4] + tt.y * er[4 * r4 + 1] + tt.z * er[4 * r4 + 2] + tt.w * er[4 * r4 + 3];
        }
        s_pool[j * 68 + lane] = acc;
      }
    }
    __syncthreads();
  }

  // ---- coeff phase: c = t&255, j-half = t>>8 ----
  {
    int c = t & 255, jh = t >> 8;
    float xm[64];
    #pragma unroll
    for (int r = 0; r < F; ++r) xm[r] = xmix[r * C + c];
    float a0 = 0.f, a1 = 0.f, a2 = 0.f;
    int j0 = jh << 6;
    for (int jj = 0; jj < 64; ++jj) {
      int j = j0 + jj;
      float4 dq = s_dxn[j];
      float acc = 0.f;
      const float4* h4 = (const float4*)(&s_pool[j * 68]);
      #pragma unroll
      for (int r4 = 0; r4 < 16; ++r4) {
        float4 hh = h4[r4];
        acc += hh.x * xm[4 * r4] + hh.y * xm[4 * r4 + 1] + hh.z * xm[4 * r4 + 2] + hh.w * xm[4 * r4 + 3];
      }
      float s = s_inv[j] * tanh_f(acc);
      a0 += dq.x * s; a1 += dq.y * s; a2 += dq.z * s;
    }
    s_cpart[(jh * 256 + c) * 3 + 0] = a0;
    s_cpart[(jh * 256 + c) * 3 + 1] = a1;
    s_cpart[(jh * 256 + c) * 3 + 2] = a2;
  }
  __syncthreads();

  // ---- attention phase (wave-parallel) + hcin combine ----
  {
    int hh = w & 3;
    int jdx = ((w >> 2) << 6) + lane;
    float lg = semb[hh];
    const float4* h4 = (const float4*)(&s_pool[jdx * 68]);
    #pragma unroll
    for (int r4 = 0; r4 < 16; ++r4) {
      float4 hv = h4[r4];
      lg += hv.x * s_semw[(4 * r4) * H + hh] + hv.y * s_semw[(4 * r4 + 1) * H + hh]
          + hv.z * s_semw[(4 * r4 + 2) * H + hh] + hv.w * s_semw[(4 * r4 + 3) * H + hh];
    }
    lg = lg > 0.f ? lg : 2.0f * (__expf(0.5f * lg) - 1.0f);  // celu alpha=2
    if (jdx == i) lg -= 1e5f;
    float mx = lg;
    #pragma unroll
    for (int off = 32; off > 0; off >>= 1) mx = fmaxf(mx, __shfl_xor(mx, off));
    if (lane == 0) s_wred[w] = mx;
    if (t < 256) {  // combine coeff partials -> hcin
      float q0 = (s_cpart[t * 3 + 0] + s_cpart[(256 + t) * 3 + 0]) * invN;
      float q1 = (s_cpart[t * 3 + 1] + s_cpart[(256 + t) * 3 + 1]) * invN;
      float q2 = (s_cpart[t * 3 + 2] + s_cpart[(256 + t) * 3 + 2]) * invN;
      s_hcin[t] = q0 * q0 + q1 * q1 + q2 * q2;
    }
    __syncthreads();
    float m = fmaxf(s_wred[w], s_wred[w ^ 4]);
    float e = __expf(lg - m);
    float sm = e;
    #pragma unroll
    for (int off = 32; off > 0; off >>= 1) sm += __shfl_xor(sm, off);
    if (lane == 0) s_wsum[w] = sm;
    __syncthreads();
    float ssum = s_wsum[w] + s_wsum[w ^ 4];
    s_att[jdx * H + hh] = e / ssum;
  }
  __syncthreads();

  // ---- h_e phase: 256 outputs x 2 j-halves ----
  {
    int idx = t & 255, jh = t >> 8;
    int f = idx >> 2, hh = idx & 3;
    float acc = 0.f;
    int j0 = jh << 6;
    #pragma unroll 8
    for (int jj = 0; jj < 64; ++jj) {
      int j = j0 + jj;
      acc += s_pool[j * 68 + f] * s_att[j * H + hh];
    }
    s_hEp[jh * 256 + idx] = acc;
  }
  __syncthreads();
  if (t < 256) s_cat[64 + t] = s_hEp[t] + s_hEp[256 + t];
  if (t < 64) s_cat[t] = s_hi[t];

  // ---- node phase ----
  {
    int r0 = w * 32;
    float acc = 0.f;
    #pragma unroll
    for (int rr = 0; rr < 32; ++rr) acc += s_hcin[r0 + rr] * p1w[(r0 + rr) * F + lane];
    s_part[w * 64 + lane] = acc;
  }
  __syncthreads();
  if (t < F) {
    float s = p1b[t];
    #pragma unroll
    for (int ww = 0; ww < 8; ++ww) s += s_part[ww * 64 + t];
    s_vec[t] = silu_f(s);
  }
  __syncthreads();
  if (w < 2) {
    int r0 = w * 32;
    float acc = 0.f;
    #pragma unroll
    for (int rr = 0; rr < 32; ++rr) acc += s_vec[r0 + rr] * p2w[(r0 + rr) * F + lane];
    s_part[w * 64 + lane] = acc;
  }
  __syncthreads();
  if (t < F) s_cat[320 + t] = silu_f(s_part[t] + s_part[64 + t] + p2b[t]);
  __syncthreads();
  {
    int r0 = w * 48;
    float acc = 0.f;
    #pragma unroll
    for (int rr = 0; rr < 48; ++rr) acc += s_cat[r0 + rr] * n1w[(r0 + rr) * F + lane];
    s_part[w * 64 + lane] = acc;
  }
  __syncthreads();
  if (t < F) {
    float s = n1b[t];
    #pragma unroll
    for (int ww = 0; ww < 8; ++ww) s += s_part[ww * 64 + t];
    s_vec[t] = silu_f(s);
  }
  __syncthreads();
  if (w < 2) {
    int r0 = w * 32;
    float acc = 0.f;
    #pragma unroll
    for (int rr = 0; rr < 32; ++rr) acc += s_vec[r0 + rr] * n2w[(r0 + rr) * F + lane];
    s_part[w * 64 + lane] = acc;
  }
  __syncthreads();
  if (t < F) {
    float hn = s_hi[t] + silu_f(s_part[t] + s_part[64 + t] + n2b[t]);
    s_hnew[t] = hn;
    hw[(bN + i) * F + t] = hn;
  }
  __syncthreads();

  if (PRE) {  // next-step node precomp from updated h
    if (t < 228) {
      float acc = 0.f;
      if (t < 50) { int k = t;
        #pragma unroll 16
        for (int r = 0; r < F; ++r) acc += s_hnew[r] * ein_w[r * K + k];
        hkA_out[(bN + i) * K + k] = acc;
      } else if (t < 100) { int k = t - 50;
        #pragma unroll 16
        for (int r = 0; r < F; ++r) acc += s_hnew[r] * ein_w[(F + r) * K + k];
        hkB_out[(bN + i) * K + k] = acc;
      } else if (t < 164) { int c = t - 100;
        #pragma unroll 16
        for (int r = 0; r < F; ++r) acc += s_hnew[r] * eo1w[r * F + c];
        e1A_out[(bN + i) * F + c] = acc;
      } else { int c = t - 164;
        #pragma unroll 16
        for (int r = 0; r < F; ++r) acc += s_hnew[r] * eo1w[(F + r) * F + c];
        e1B_out[(bN + i) * F + c] = acc;
      }
    }
  }
  if (TAIL) {  // coord1 halves + vel scalar m for the flow tail
    if (w == 0) {
      float acc = 0.f;
      #pragma unroll 16
      for (int r = 0; r < F; ++r) acc += s_hnew[r] * c1w[r * F + lane];
      uA[(bN + i) * F + lane] = acc;
    } else if (w == 1) {
      float acc = 0.f;
      #pragma unroll 16
      for (int r = 0; r < F; ++r) acc += s_hnew[r] * c1w[(F + r) * F + lane];
      uB[(bN + i) * F + lane] = acc;
    } else if (w == 2) {
      float acc = v1b[lane];
      #pragma unroll 16
      for (int r = 0; r < F; ++r) acc += s_hnew[r] * v1w[r * F + lane];
      float tv = silu_f(acc) * v2w[lane];
      #pragma unroll
      for (int off = 32; off > 0; off >>= 1) tv += __shfl_down(tv, off);
      if (lane == 0) mbuf[bN + i] = tv;
    }
  }
}

// delta_v[b,i] = (1/N) sum_j (coord2 . silu(uA_i + uB_j + b)) * (x_i - x_j)
__global__ __launch_bounds__(256) void k_tail(const float* __restrict__ xb,
    const float* __restrict__ uA, const float* __restrict__ uB,
    const float* __restrict__ c1b, const float* __restrict__ c2w,
    float* __restrict__ dv) {
  int blk = blockIdx.x, b = blk >> 7, i = blk & 127;
  int t = threadIdx.x, w = t >> 6, lane = t & 63;
  __shared__ float s_xpos[N * 3];
  __shared__ float s_uAi[F];
  __shared__ float s_acc[4][3];
  for (int idx = t; idx < N * 3; idx += 256) s_xpos[idx] = xb[b * N * 3 + idx];
  if (t < F) s_uAi[t] = uA[(b * N + i) * F + t];
  __syncthreads();
  float xi0 = s_xpos[i * 3 + 0], xi1 = s_xpos[i * 3 + 1], xi2 = s_xpos[i * 3 + 2];
  float base = s_uAi[lane] + c1b[lane];
  float c2v = c2w[lane];
  float a0 = 0.f, a1 = 0.f, a2 = 0.f;
  for (int jj = 0; jj < 32; ++jj) {
    int j = w + 4 * jj;
    float tv = silu_f(base + uB[(b * N + j) * F + lane]) * c2v;
    #pragma unroll
    for (int off = 32; off > 0; off >>= 1) tv += __shfl_down(tv, off);
    if (lane == 0) {
      float dx0 = xi0 - s_xpos[j * 3 + 0];
      float dx1 = xi1 - s_xpos[j * 3 + 1];
      float dx2 = xi2 - s_xpos[j * 3 + 2];
      a0 += tv * dx0; a1 += tv * dx1; a2 += tv * dx2;
    }
  }
  if (lane == 0) { s_acc[w][0] = a0; s_acc[w][1] = a1; s_acc[w][2] = a2; }
  __syncthreads();
  if (t < 3) {
    float s = s_acc[0][t] + s_acc[1][t] + s_acc[2][t] + s_acc[3][t];
    dv[(b * N + i) * 3 + t] = s * (1.0f / (float)N);
  }
}

// apply v' = exp(m)*v + dv, x' = x + v'; center x and v; sld += 3*sum(m). One block per batch.
__global__ __launch_bounds__(128) void k_fin(float* __restrict__ xb, float* __restrict__ vb,
    const float* __restrict__ dv, const float* __restrict__ mbuf, float* __restrict__ sld) {
  int b = blockIdx.x, t = threadIdx.x;
  __shared__ float red[N];
  float m = mbuf[b * N + t];
  float em = __expf(m);
  float vv[3], xx[3];
  #pragma unroll
  for (int d = 0; d < 3; ++d) {
    int idx = (b * N + t) * 3 + d;
    vv[d] = em * vb[idx] + dv[idx];
    xx[d] = xb[idx] + vv[d];
  }
  #pragma unroll
  for (int d = 0; d < 3; ++d) {
    red[t] = xx[d];
    __syncthreads();
    for (int s = 64; s > 0; s >>= 1) { if (t < s) red[t] += red[t + s]; __syncthreads(); }
    xx[d] -= red[0] * (1.0f / (float)N);
    __syncthreads();
    red[t] = vv[d];
    __syncthreads();
    for (int s = 64; s > 0; s >>= 1) { if (t < s) red[t] += red[t + s]; __syncthreads(); }
    vv[d] -= red[0] * (1.0f / (float)N);
    __syncthreads();
  }
  #pragma unroll
  for (int d = 0; d < 3; ++d) {
    int idx = (b * N + t) * 3 + d;
    xb[idx] = xx[d];
    vb[idx] = vv[d];
  }
  red[t] = m;
  __syncthreads();
  for (int s = 64; s > 0; s >>= 1) { if (t < s) red[t] += red[t + s]; __syncthreads(); }
  if (t == 0) sld[b] += 3.0f * red[0];
}

__global__ void k_out(const float* __restrict__ xw, const float* __restrict__ vw,
                      const float* __restrict__ sld, float* __restrict__ out) {
  int t = blockIdx.x * blockDim.x + threadIdx.x;
  if (t < B * N * 3) { out[t] = xw[t]; out[B * N * 3 + t] = vw[t]; }
  if (t < B) out[2 * B * N * 3 + t] = sld[t];
}

}  // namespace

extern "C" void kernel_launch(void* const* d_in, const int* in_sizes, int n_in,
                              void* d_out, int out_size, void* d_ws, size_t ws_size,
                              hipStream_t stream) {
  const float* in_h   = (const float*)d_in[0];
  const float* in_x   = (const float*)d_in[1];
  const float* in_v   = (const float*)d_in[2];
  const float* emb1_w = (const float*)d_in[3];
  const float* emb1_b = (const float*)d_in[4];
  const float* emb2_w = (const float*)d_in[5];
  const float* emb2_b = (const float*)d_in[6];
  const float* ein_w  = (const float*)d_in[7];
  const float* ein_b  = (const float*)d_in[8];
  const float* rbf_m  = (const float*)d_in[9];
  const float* rbf_b  = (const float*)d_in[10];
  const float* eo1w   = (const float*)d_in[11];
  const float* eo1b   = (const float*)d_in[12];
  const float* eo2w   = (const float*)d_in[13];
  const float* eo2b   = (const float*)d_in[14];
  const float* xmix   = (const float*)d_in[15];
  const float* p1w    = (const float*)d_in[16];
  const float* p1b    = (const float*)d_in[17];
  const float* p2w    = (const float*)d_in[18];
  const float* p2b    = (const float*)d_in[19];
  const float* semw   = (const float*)d_in[20];
  const float* semb   = (const float*)d_in[21];
  const float* n1w    = (const float*)d_in[22];
  const float* n1b    = (const float*)d_in[23];
  const float* n2w    = (const float*)d_in[24];
  const float* n2b    = (const float*)d_in[25];
  const float* v1w    = (const float*)d_in[26];
  const float* v1b    = (const float*)d_in[27];
  const float* v2w    = (const float*)d_in[28];
  const float* c1w    = (const float*)d_in[29];
  const float* c1b    = (const float*)d_in[30];
  const float* c2w    = (const float*)d_in[31];

  float* ws   = (float*)d_ws;
  float* h0   = ws;                 // BN*F
  float* hw   = h0 + BN * F;        // BN*F
  float* hkA0 = hw + BN * F;        // BN*K
  float* hkB0 = hkA0 + BN * K;
  float* e1A0 = hkB0 + BN * K;      // BN*F
  float* e1B0 = e1A0 + BN * F;
  float* hkA1 = e1B0 + BN * F;
  float* hkB1 = hkA1 + BN * K;
  float* e1A1 = hkB1 + BN * K;
  float* e1B1 = e1A1 + BN * F;
  float* uA   = e1B1 + BN * F;      // BN*F
  float* uB   = uA + BN * F;
  float* xw   = uB + BN * F;        // BN*3
  float* vw   = xw + BN * 3;
  float* dvb  = vw + BN * 3;
  float* mbuf = dvb + BN * 3;       // BN
  float* sld  = mbuf + BN;          // B

  k_init<<<6, 256, 0, stream>>>(in_x, in_v, xw, vw, sld);
  k_embed<<<BN, F, 0, stream>>>(in_h, emb1_w, emb1_b, emb2_w, emb2_b, h0);

  float* hkA[2] = {hkA0, hkA1};
  float* hkB[2] = {hkB0, hkB1};
  float* e1A[2] = {e1A0, e1A1};
  float* e1B[2] = {e1B0, e1B1};

  for (int dep = 0; dep < 2; ++dep) {
    for (int half = 0; half < 2; ++half) {
      int l = 2 * dep + half;
      float* xb = half ? vw : xw;
      float* vb = half ? xw : vw;
      const float* einw_l = ein_w + l * 2 * F * K;
      const float* einb_l = ein_b + l * K;
      const float* rbm_l  = rbf_m + l * K;
      const float* rbb_l  = rbf_b + l * K;
      const float* eo1w_l = eo1w + l * 179 * F;
      const float* eo1b_l = eo1b + l * F;
      const float* eo2w_l = eo2w + l * F * F;
      const float* eo2b_l = eo2b + l * F;
      const float* xmix_l = xmix + l * F * C;
      const float* p1w_l  = p1w + l * C * F;
      const float* p1b_l  = p1b + l * F;
      const float* p2w_l  = p2w + l * F * F;
      const float* p2b_l  = p2b + l * F;
      const float* semw_l = semw + l * F * H;
      const float* semb_l = semb + l * H;
      const float* n1w_l  = n1w + l * 384 * F;
      const float* n1b_l  = n1b + l * F;
      const float* n2w_l  = n2w + l * F * F;
      const float* n2b_l  = n2b + l * F;
      const float* v1w_l  = v1w + l * F * F;
      const float* v1b_l  = v1b + l * F;
      const float* v2w_l  = v2w + l * F;
      const float* c1w_l  = c1w + l * 2 * F * F;
      const float* c1b_l  = c1b + l * F;
      const float* c2w_l  = c2w + l * F;

      k_pre<<<BN, 256, 0, stream>>>(h0, hw, einw_l, eo1w_l, hkA[0], hkB[0], e1A[0], e1B[0]);
      // step 0: in set0 -> out set1 ; step 1: in set1 -> out set0 ; step 2: in set0, tail
      k_mp<1, 0><<<BN, 512, 0, stream>>>(hw, xb, hkA[0], hkB[0], e1A[0], e1B[0],
          einb_l, rbm_l, rbb_l, eo1w_l, eo1b_l, eo2w_l, eo2b_l, xmix_l,
          p1w_l, p1b_l, p2w_l, p2b_l, semw_l, semb_l, n1w_l, n1b_l, n2w_l, n2b_l,
          einw_l, hkA[1], hkB[1], e1A[1], e1B[1],
          c1w_l, v1w_l, v1b_l, v2w_l, uA, uB, mbuf);
      k_mp<1, 0><<<BN, 512, 0, stream>>>(hw, xb, hkA[1], hkB[1], e1A[1], e1B[1],
          einb_l, rbm_l, rbb_l, eo1w_l, eo1b_l, eo2w_l, eo2b_l, xmix_l,
          p1w_l, p1b_l, p2w_l, p2b_l, semw_l, semb_l, n1w_l, n1b_l, n2w_l, n2b_l,
          einw_l, hkA[0], hkB[0], e1A[0], e1B[0],
          c1w_l, v1w_l, v1b_l, v2w_l, uA, uB, mbuf);
      k_mp<0, 1><<<BN, 512, 0, stream>>>(hw, xb, hkA[0], hkB[0], e1A[0], e1B[0],
          einb_l, rbm_l, rbb_l, eo1w_l, eo1b_l, eo2w_l, eo2b_l, xmix_l,
          p1w_l, p1b_l, p2w_l, p2b_l, semw_l, semb_l, n1w_l, n1b_l, n2w_l, n2b_l,
          einw_l, hkA[1], hkB[1], e1A[1], e1B[1],
          c1w_l, v1w_l, v1b_l, v2w_l, uA, uB, mbuf);
      k_tail<<<BN, 256, 0, stream>>>(xb, uA, uB, c1b_l, c2w_l, dvb);
      k_fin<<<B, 128, 0, stream>>>(xb, vb, dvb, mbuf, sld);
    }
  }
  k_out<<<6, 256, 0, stream>>>(xw, vw, sld, (float*)d_out);
}

// Round 2
// 1400.465 us; speedup vs baseline: 1.7689x; 1.7689x over previous
//
#include <hip/hip_runtime.h>
#include <math.h>

namespace {

constexpr int B = 4, N = 128, FIN = 16, F = 64, H = 4, K = 50, C = 256;
constexpr int BN = B * N;
constexpr float EPS = 1e-5f;

__device__ __forceinline__ float silu_f(float x) { return x / (1.0f + __expf(-x)); }
__device__ __forceinline__ float tanh_f(float x) { return 1.0f - 2.0f / (__expf(2.0f * x) + 1.0f); }

__global__ void k_init(const float* __restrict__ x, const float* __restrict__ v,
                       float* __restrict__ xw, float* __restrict__ vw, float* __restrict__ sld) {
  int t = blockIdx.x * blockDim.x + threadIdx.x;
  if (t < B * N * 3) { xw[t] = x[t]; vw[t] = v[t]; }
  if (t < B) sld[t] = 0.0f;
}

__global__ __launch_bounds__(F) void k_embed(const float* __restrict__ hin,
    const float* __restrict__ w1, const float* __restrict__ b1,
    const float* __restrict__ w2, const float* __restrict__ b2, float* __restrict__ h0) {
  int node = blockIdx.x, f = threadIdx.x;
  __shared__ float t1[F];
  float acc = b1[f];
  #pragma unroll
  for (int r = 0; r < FIN; ++r) acc += hin[node * FIN + r] * w1[r * F + f];
  t1[f] = silu_f(acc);
  __syncthreads();
  float a0 = b2[f], a1 = 0.f, a2 = 0.f, a3 = 0.f;
  #pragma unroll
  for (int r = 0; r < F; r += 4) {
    a0 += t1[r] * w2[r * F + f];
    a1 += t1[r + 1] * w2[(r + 1) * F + f];
    a2 += t1[r + 2] * w2[(r + 2) * F + f];
    a3 += t1[r + 3] * w2[(r + 3) * F + f];
  }
  h0[node * F + f] = (a0 + a1) + (a2 + a3);
}

// Per-node precomputation at flow start: hkA/hkB (edge_in halves), e1A/e1B (eo1 halves).
__global__ __launch_bounds__(256) void k_pre(const float* __restrict__ h0, float* __restrict__ hw,
    const float* __restrict__ ein_w, const float* __restrict__ eo1w,
    float* __restrict__ hkA, float* __restrict__ hkB,
    float* __restrict__ e1A, float* __restrict__ e1B) {
  int node = blockIdx.x, t = threadIdx.x;
  __shared__ float s_h[F];
  if (t < F) s_h[t] = h0[node * F + t];
  __syncthreads();
  if (t < F) hw[node * F + t] = s_h[t];
  if (t < 228) {
    float a0 = 0.f, a1 = 0.f, a2 = 0.f, a3 = 0.f;
    if (t < 50) { int k = t;
      #pragma unroll
      for (int r = 0; r < F; r += 4) {
        a0 += s_h[r] * ein_w[r * K + k];       a1 += s_h[r + 1] * ein_w[(r + 1) * K + k];
        a2 += s_h[r + 2] * ein_w[(r + 2) * K + k]; a3 += s_h[r + 3] * ein_w[(r + 3) * K + k];
      }
      hkA[node * K + k] = (a0 + a1) + (a2 + a3);
    } else if (t < 100) { int k = t - 50;
      #pragma unroll
      for (int r = 0; r < F; r += 4) {
        a0 += s_h[r] * ein_w[(F + r) * K + k];       a1 += s_h[r + 1] * ein_w[(F + r + 1) * K + k];
        a2 += s_h[r + 2] * ein_w[(F + r + 2) * K + k]; a3 += s_h[r + 3] * ein_w[(F + r + 3) * K + k];
      }
      hkB[node * K + k] = (a0 + a1) + (a2 + a3);
    } else if (t < 164) { int c = t - 100;
      #pragma unroll
      for (int r = 0; r < F; r += 4) {
        a0 += s_h[r] * eo1w[r * F + c];       a1 += s_h[r + 1] * eo1w[(r + 1) * F + c];
        a2 += s_h[r + 2] * eo1w[(r + 2) * F + c]; a3 += s_h[r + 3] * eo1w[(r + 3) * F + c];
      }
      e1A[node * F + c] = (a0 + a1) + (a2 + a3);
    } else { int c = t - 164;
      #pragma unroll
      for (int r = 0; r < F; r += 4) {
        a0 += s_h[r] * eo1w[(F + r) * F + c];       a1 += s_h[r + 1] * eo1w[(F + r + 1) * F + c];
        a2 += s_h[r + 2] * eo1w[(F + r + 2) * F + c]; a3 += s_h[r + 3] * eo1w[(F + r + 3) * F + c];
      }
      e1B[node * F + c] = (a0 + a1) + (a2 + a3);
    }
  }
}

// Fused message-passing step for one (b,i): 256 threads / 4 waves.
// Edge MLP split into two per-wave sub-passes (t1 then he) so only one weight array is
// register-live at a time; all GEMM loops use 4 accumulators to break FMA dep chains;
// softmax is shuffle-based (3 barriers).
template<int PRE, int TAIL>
__global__ __launch_bounds__(256, 2) void k_mp(
    float* __restrict__ hw, const float* __restrict__ xp,
    const float* __restrict__ hkA_in, const float* __restrict__ hkB_in,
    const float* __restrict__ e1A_in, const float* __restrict__ e1B_in,
    const float* __restrict__ ein_b, const float* __restrict__ rbf_m, const float* __restrict__ rbf_b,
    const float* __restrict__ eo1w, const float* __restrict__ eo1b,
    const float* __restrict__ eo2w, const float* __restrict__ eo2b,
    const float* __restrict__ xmix,
    const float* __restrict__ p1w, const float* __restrict__ p1b,
    const float* __restrict__ p2w, const float* __restrict__ p2b,
    const float* __restrict__ semw, const float* __restrict__ semb,
    const float* __restrict__ n1w, const float* __restrict__ n1b,
    const float* __restrict__ n2w, const float* __restrict__ n2b,
    const float* __restrict__ ein_w,
    float* __restrict__ hkA_out, float* __restrict__ hkB_out,
    float* __restrict__ e1A_out, float* __restrict__ e1B_out,
    const float* __restrict__ c1w, const float* __restrict__ v1w, const float* __restrict__ v1b,
    const float* __restrict__ v2w,
    float* __restrict__ uA, float* __restrict__ uB, float* __restrict__ mbuf) {
  int blk = blockIdx.x, b = blk >> 7, i = blk & 127;
  int t = threadIdx.x, w = t >> 6, lane = t & 63;
  int bN = b * N;
  constexpr float invN = 1.0f / (float)N;

  __shared__ __align__(16) float s_pool[128 * 68];   // t1 then he, row j = 68 floats
  __shared__ __align__(16) float s_zk[4][56];
  __shared__ __align__(16) float4 s_dxn[N];          // (dx0,dx1,dx2,dn)
  __shared__ float s_inv[N];                         // 1/(dn+EPS)
  __shared__ float s_xpos[N * 3];
  __shared__ float s_hi[F];
  __shared__ float s_zkbase[K];
  __shared__ float s_e1base[F];
  __shared__ __align__(16) float s_attT[H][N];       // att transposed: [head][j]
  __shared__ float s_wred[8];
  __shared__ float s_wsum[8];
  __shared__ float s_hcin[C];
  __shared__ float s_part[4][F];
  __shared__ float s_vec[F];
  __shared__ float s_hnew[F];
  __shared__ float s_cat[384];

  // ---- staging ----
  for (int idx = t; idx < N * 3; idx += 256) s_xpos[idx] = xp[bN * 3 + idx];
  if (t < F) s_hi[t] = hw[(bN + i) * F + t];
  if (t < K) s_zkbase[t] = hkA_in[(bN + i) * K + t] + ein_b[t];
  if (t >= 64 && t < 128) s_e1base[t - 64] = e1A_in[(bN + i) * F + (t - 64)] + eo1b[t - 64];
  if (lane >= 50 && lane < 56) s_zk[w][lane] = 0.f;  // float4 pad
  __syncthreads();
  if (t < N) {
    float dx0 = s_xpos[i * 3 + 0] - s_xpos[t * 3 + 0];
    float dx1 = s_xpos[i * 3 + 1] - s_xpos[t * 3 + 1];
    float dx2 = s_xpos[i * 3 + 2] - s_xpos[t * 3 + 2];
    float dn = sqrtf(dx0 * dx0 + dx1 * dx1 + dx2 * dx2 + EPS * EPS);
    s_dxn[t] = make_float4(dx0, dx1, dx2, dn);
    s_inv[t] = 1.0f / (dn + EPS);
  }
  __syncthreads();

  float rbm = 0.f, rbb = 0.f;
  if (lane < K) { rbm = rbf_m[lane]; rbb = rbf_b[lane]; }

  // ---- edge sub-pass A: t1 for this wave's 32 rows (only wk live) ----
  {
    float wk[52];
    #pragma unroll
    for (int k = 0; k < 50; ++k) wk[k] = eo1w[(128 + k) * F + lane];
    wk[50] = 0.f; wk[51] = 0.f;
    float w1d = eo1w[178 * F + lane];
    for (int jj = 0; jj < 32; ++jj) {
      int j = w + 4 * jj;
      float dn = s_dxn[j].w;
      if (lane < K) {
        float hk = s_zkbase[lane] + hkB_in[(bN + j) * K + lane];
        float e = __expf(-dn) - rbm;
        s_zk[w][lane] = __expf(-rbb * e * e) * hk;
      }
      float e1Bv = e1B_in[(bN + j) * F + lane];
      float ac0 = s_e1base[lane] + e1Bv + dn * w1d, ac1 = 0.f, ac2 = 0.f, ac3 = 0.f;
      const float4* z4 = (const float4*)(&s_zk[w][0]);
      #pragma unroll
      for (int k4 = 0; k4 < 13; ++k4) {
        float4 z = z4[k4];
        ac0 += z.x * wk[4 * k4];     ac1 += z.y * wk[4 * k4 + 1];
        ac2 += z.z * wk[4 * k4 + 2]; ac3 += z.w * wk[4 * k4 + 3];
      }
      s_pool[j * 68 + lane] = silu_f((ac0 + ac1) + (ac2 + ac3));
    }
  }
  // no barrier: each wave owns its own rows (same-wave LDS ops are in order)
  // ---- edge sub-pass B: he = t1 @ eo2 (only er live), overwrite rows in place ----
  {
    float er[64];
    #pragma unroll
    for (int r = 0; r < F; ++r) er[r] = eo2w[r * F + lane];
    float b2 = eo2b[lane];
    for (int jj = 0; jj < 32; ++jj) {
      int j = w + 4 * jj;
      const float4* t4 = (const float4*)(&s_pool[j * 68]);
      float ac0 = b2, ac1 = 0.f, ac2 = 0.f, ac3 = 0.f;
      #pragma unroll
      for (int r4 = 0; r4 < 16; ++r4) {
        float4 tt = t4[r4];
        ac0 += tt.x * er[4 * r4];     ac1 += tt.y * er[4 * r4 + 1];
        ac2 += tt.z * er[4 * r4 + 2]; ac3 += tt.w * er[4 * r4 + 3];
      }
      s_pool[j * 68 + lane] = (ac0 + ac1) + (ac2 + ac3);
    }
  }
  __syncthreads();

  // ---- coeff phase: thread t owns coefficient column c=t ----
  {
    float xm[64];
    #pragma unroll
    for (int r = 0; r < F; ++r) xm[r] = xmix[r * C + t];
    float a0 = 0.f, a1 = 0.f, a2 = 0.f;
    for (int j = 0; j < N; ++j) {
      float4 dq = s_dxn[j];
      const float4* h4 = (const float4*)(&s_pool[j * 68]);
      float ac0 = 0.f, ac1 = 0.f, ac2 = 0.f, ac3 = 0.f;
      #pragma unroll
      for (int r4 = 0; r4 < 16; ++r4) {
        float4 hh = h4[r4];
        ac0 += hh.x * xm[4 * r4];     ac1 += hh.y * xm[4 * r4 + 1];
        ac2 += hh.z * xm[4 * r4 + 2]; ac3 += hh.w * xm[4 * r4 + 3];
      }
      float s = s_inv[j] * tanh_f((ac0 + ac1) + (ac2 + ac3));
      a0 += dq.x * s; a1 += dq.y * s; a2 += dq.z * s;
    }
    a0 *= invN; a1 *= invN; a2 *= invN;
    s_hcin[t] = a0 * a0 + a1 * a1 + a2 * a2;
  }

  // ---- attention phase: thread t -> j = t&127, heads {2g, 2g+1}, g = t>>7 ----
  {
    int g = t >> 7, j = t & 127;
    int h0 = 2 * g, h1 = h0 + 1;
    float l0 = semb[h0], l1 = semb[h1];
    const float4* h4 = (const float4*)(&s_pool[j * 68]);
    #pragma unroll
    for (int r4 = 0; r4 < 16; ++r4) {
      float4 hv = h4[r4];
      l0 += hv.x * semw[(4 * r4) * H + h0] + hv.y * semw[(4 * r4 + 1) * H + h0]
          + hv.z * semw[(4 * r4 + 2) * H + h0] + hv.w * semw[(4 * r4 + 3) * H + h0];
      l1 += hv.x * semw[(4 * r4) * H + h1] + hv.y * semw[(4 * r4 + 1) * H + h1]
          + hv.z * semw[(4 * r4 + 2) * H + h1] + hv.w * semw[(4 * r4 + 3) * H + h1];
    }
    l0 = l0 > 0.f ? l0 : 2.0f * (__expf(0.5f * l0) - 1.0f);  // celu alpha=2
    l1 = l1 > 0.f ? l1 : 2.0f * (__expf(0.5f * l1) - 1.0f);
    if (j == i) { l0 -= 1e5f; l1 -= 1e5f; }
    float m0 = l0, m1 = l1;
    #pragma unroll
    for (int off = 32; off > 0; off >>= 1) {
      m0 = fmaxf(m0, __shfl_xor(m0, off));
      m1 = fmaxf(m1, __shfl_xor(m1, off));
    }
    if (lane == 0) { s_wred[w * 2] = m0; s_wred[w * 2 + 1] = m1; }
    __syncthreads();
    int pw = w ^ 1;  // partner wave covers the other 64 j's of the same heads
    float M0 = fmaxf(s_wred[w * 2], s_wred[pw * 2]);
    float M1 = fmaxf(s_wred[w * 2 + 1], s_wred[pw * 2 + 1]);
    float e0 = __expf(l0 - M0), e1 = __expf(l1 - M1);
    float sm0 = e0, sm1 = e1;
    #pragma unroll
    for (int off = 32; off > 0; off >>= 1) {
      sm0 += __shfl_xor(sm0, off);
      sm1 += __shfl_xor(sm1, off);
    }
    if (lane == 0) { s_wsum[w * 2] = sm0; s_wsum[w * 2 + 1] = sm1; }
    __syncthreads();
    float S0 = s_wsum[w * 2] + s_wsum[pw * 2];
    float S1 = s_wsum[w * 2 + 1] + s_wsum[pw * 2 + 1];
    s_attT[h0][j] = e0 / S0;
    s_attT[h1][j] = e1 / S1;
  }
  __syncthreads();

  // ---- h_e phase: thread t -> (f = t>>2, head = t&3); att rows vectorized ----
  {
    int f = t >> 2, hh = t & 3;
    const float4* a4 = (const float4*)(&s_attT[hh][0]);
    float ac0 = 0.f, ac1 = 0.f, ac2 = 0.f, ac3 = 0.f;
    #pragma unroll 8
    for (int jg = 0; jg < 32; ++jg) {
      float4 av = a4[jg];
      int j0 = jg * 4;
      ac0 += s_pool[(j0 + 0) * 68 + f] * av.x;
      ac1 += s_pool[(j0 + 1) * 68 + f] * av.y;
      ac2 += s_pool[(j0 + 2) * 68 + f] * av.z;
      ac3 += s_pool[(j0 + 3) * 68 + f] * av.w;
    }
    s_cat[64 + t] = (ac0 + ac1) + (ac2 + ac3);   // h_e slot of concat
  }

  // ---- node phase ----
  {
    int c0 = w * 64;
    float a0 = 0.f, a1 = 0.f, a2 = 0.f, a3 = 0.f;
    #pragma unroll 8
    for (int cc = 0; cc < 64; cc += 4) {
      a0 += s_hcin[c0 + cc] * p1w[(c0 + cc) * F + lane];
      a1 += s_hcin[c0 + cc + 1] * p1w[(c0 + cc + 1) * F + lane];
      a2 += s_hcin[c0 + cc + 2] * p1w[(c0 + cc + 2) * F + lane];
      a3 += s_hcin[c0 + cc + 3] * p1w[(c0 + cc + 3) * F + lane];
    }
    s_part[w][lane] = (a0 + a1) + (a2 + a3);
  }
  __syncthreads();
  if (t < F) s_vec[t] = silu_f(s_part[0][t] + s_part[1][t] + s_part[2][t] + s_part[3][t] + p1b[t]);
  __syncthreads();
  if (t < F) {
    float a0 = p2b[t], a1 = 0.f, a2 = 0.f, a3 = 0.f;
    #pragma unroll 8
    for (int r = 0; r < F; r += 4) {
      a0 += s_vec[r] * p2w[r * F + t];
      a1 += s_vec[r + 1] * p2w[(r + 1) * F + t];
      a2 += s_vec[r + 2] * p2w[(r + 2) * F + t];
      a3 += s_vec[r + 3] * p2w[(r + 3) * F + t];
    }
    s_cat[t] = s_hi[t];
    s_cat[320 + t] = silu_f((a0 + a1) + (a2 + a3));
  }
  __syncthreads();
  {
    int r0 = w * 96;
    float a0 = 0.f, a1 = 0.f, a2 = 0.f, a3 = 0.f;
    #pragma unroll 8
    for (int rr = 0; rr < 96; rr += 4) {
      a0 += s_cat[r0 + rr] * n1w[(r0 + rr) * F + lane];
      a1 += s_cat[r0 + rr + 1] * n1w[(r0 + rr + 1) * F + lane];
      a2 += s_cat[r0 + rr + 2] * n1w[(r0 + rr + 2) * F + lane];
      a3 += s_cat[r0 + rr + 3] * n1w[(r0 + rr + 3) * F + lane];
    }
    s_part[w][lane] = (a0 + a1) + (a2 + a3);
  }
  __syncthreads();
  if (t < F) s_vec[t] = silu_f(s_part[0][t] + s_part[1][t] + s_part[2][t] + s_part[3][t] + n1b[t]);
  __syncthreads();
  if (t < F) {
    float a0 = n2b[t], a1 = 0.f, a2 = 0.f, a3 = 0.f;
    #pragma unroll 8
    for (int r = 0; r < F; r += 4) {
      a0 += s_vec[r] * n2w[r * F + t];
      a1 += s_vec[r + 1] * n2w[(r + 1) * F + t];
      a2 += s_vec[r + 2] * n2w[(r + 2) * F + t];
      a3 += s_vec[r + 3] * n2w[(r + 3) * F + t];
    }
    float hn = s_hi[t] + silu_f((a0 + a1) + (a2 + a3));
    s_hnew[t] = hn;
    hw[(bN + i) * F + t] = hn;
  }
  __syncthreads();

  if (PRE) {  // next-step node precomp from updated h
    if (t < 228) {
      float a0 = 0.f, a1 = 0.f, a2 = 0.f, a3 = 0.f;
      if (t < 50) { int k = t;
        #pragma unroll
        for (int r = 0; r < F; r += 4) {
          a0 += s_hnew[r] * ein_w[r * K + k];       a1 += s_hnew[r + 1] * ein_w[(r + 1) * K + k];
          a2 += s_hnew[r + 2] * ein_w[(r + 2) * K + k]; a3 += s_hnew[r + 3] * ein_w[(r + 3) * K + k];
        }
        hkA_out[(bN + i) * K + k] = (a0 + a1) + (a2 + a3);
      } else if (t < 100) { int k = t - 50;
        #pragma unroll
        for (int r = 0; r < F; r += 4) {
          a0 += s_hnew[r] * ein_w[(F + r) * K + k];       a1 += s_hnew[r + 1] * ein_w[(F + r + 1) * K + k];
          a2 += s_hnew[r + 2] * ein_w[(F + r + 2) * K + k]; a3 += s_hnew[r + 3] * ein_w[(F + r + 3) * K + k];
        }
        hkB_out[(bN + i) * K + k] = (a0 + a1) + (a2 + a3);
      } else if (t < 164) { int c = t - 100;
        #pragma unroll
        for (int r = 0; r < F; r += 4) {
          a0 += s_hnew[r] * eo1w[r * F + c];       a1 += s_hnew[r + 1] * eo1w[(r + 1) * F + c];
          a2 += s_hnew[r + 2] * eo1w[(r + 2) * F + c]; a3 += s_hnew[r + 3] * eo1w[(r + 3) * F + c];
        }
        e1A_out[(bN + i) * F + c] = (a0 + a1) + (a2 + a3);
      } else { int c = t - 164;
        #pragma unroll
        for (int r = 0; r < F; r += 4) {
          a0 += s_hnew[r] * eo1w[(F + r) * F + c];       a1 += s_hnew[r + 1] * eo1w[(F + r + 1) * F + c];
          a2 += s_hnew[r + 2] * eo1w[(F + r + 2) * F + c]; a3 += s_hnew[r + 3] * eo1w[(F + r + 3) * F + c];
        }
        e1B_out[(bN + i) * F + c] = (a0 + a1) + (a2 + a3);
      }
    }
  }
  if (TAIL) {  // coord1 halves + vel scalar m for the flow tail
    if (w == 0) {
      float a0 = 0.f, a1 = 0.f, a2 = 0.f, a3 = 0.f;
      #pragma unroll
      for (int r = 0; r < F; r += 4) {
        a0 += s_hnew[r] * c1w[r * F + lane];       a1 += s_hnew[r + 1] * c1w[(r + 1) * F + lane];
        a2 += s_hnew[r + 2] * c1w[(r + 2) * F + lane]; a3 += s_hnew[r + 3] * c1w[(r + 3) * F + lane];
      }
      uA[(bN + i) * F + lane] = (a0 + a1) + (a2 + a3);
    } else if (w == 1) {
      float a0 = 0.f, a1 = 0.f, a2 = 0.f, a3 = 0.f;
      #pragma unroll
      for (int r = 0; r < F; r += 4) {
        a0 += s_hnew[r] * c1w[(F + r) * F + lane];       a1 += s_hnew[r + 1] * c1w[(F + r + 1) * F + lane];
        a2 += s_hnew[r + 2] * c1w[(F + r + 2) * F + lane]; a3 += s_hnew[r + 3] * c1w[(F + r + 3) * F + lane];
      }
      uB[(bN + i) * F + lane] = (a0 + a1) + (a2 + a3);
    } else if (w == 2) {
      float a0 = v1b[lane], a1 = 0.f, a2 = 0.f, a3 = 0.f;
      #pragma unroll
      for (int r = 0; r < F; r += 4) {
        a0 += s_hnew[r] * v1w[r * F + lane];       a1 += s_hnew[r + 1] * v1w[(r + 1) * F + lane];
        a2 += s_hnew[r + 2] * v1w[(r + 2) * F + lane]; a3 += s_hnew[r + 3] * v1w[(r + 3) * F + lane];
      }
      float tv = silu_f((a0 + a1) + (a2 + a3)) * v2w[lane];
      #pragma unroll
      for (int off = 32; off > 0; off >>= 1) tv += __shfl_down(tv, off);
      if (lane == 0) mbuf[bN + i] = tv;
    }
  }
}

// delta_v[b,i] = (1/N) sum_j (coord2 . silu(uA_i + uB_j + b)) * (x_i - x_j)
__global__ __launch_bounds__(256) void k_tail(const float* __restrict__ xb,
    const float* __restrict__ uA, const float* __restrict__ uB,
    const float* __restrict__ c1b, const float* __restrict__ c2w,
    float* __restrict__ dv) {
  int blk = blockIdx.x, b = blk >> 7, i = blk & 127;
  int t = threadIdx.x, w = t >> 6, lane = t & 63;
  __shared__ float s_xpos[N * 3];
  __shared__ float s_uAi[F];
  __shared__ float s_acc[4][3];
  for (int idx = t; idx < N * 3; idx += 256) s_xpos[idx] = xb[b * N * 3 + idx];
  if (t < F) s_uAi[t] = uA[(b * N + i) * F + t];
  __syncthreads();
  float xi0 = s_xpos[i * 3 + 0], xi1 = s_xpos[i * 3 + 1], xi2 = s_xpos[i * 3 + 2];
  float base = s_uAi[lane] + c1b[lane];
  float c2v = c2w[lane];
  float a0 = 0.f, a1 = 0.f, a2 = 0.f;
  for (int jj = 0; jj < 32; ++jj) {
    int j = w + 4 * jj;
    float tv = silu_f(base + uB[(b * N + j) * F + lane]) * c2v;
    #pragma unroll
    for (int off = 32; off > 0; off >>= 1) tv += __shfl_down(tv, off);
    if (lane == 0) {
      float dx0 = xi0 - s_xpos[j * 3 + 0];
      float dx1 = xi1 - s_xpos[j * 3 + 1];
      float dx2 = xi2 - s_xpos[j * 3 + 2];
      a0 += tv * dx0; a1 += tv * dx1; a2 += tv * dx2;
    }
  }
  if (lane == 0) { s_acc[w][0] = a0; s_acc[w][1] = a1; s_acc[w][2] = a2; }
  __syncthreads();
  if (t < 3) {
    float s = s_acc[0][t] + s_acc[1][t] + s_acc[2][t] + s_acc[3][t];
    dv[(b * N + i) * 3 + t] = s * (1.0f / (float)N);
  }
}

// apply v' = exp(m)*v + dv, x' = x + v'; center x and v; sld += 3*sum(m). One block per batch.
__global__ __launch_bounds__(128) void k_fin(float* __restrict__ xb, float* __restrict__ vb,
    const float* __restrict__ dv, const float* __restrict__ mbuf, float* __restrict__ sld) {
  int b = blockIdx.x, t = threadIdx.x;
  __shared__ float red[N];
  float m = mbuf[b * N + t];
  float em = __expf(m);
  float vv[3], xx[3];
  #pragma unroll
  for (int d = 0; d < 3; ++d) {
    int idx = (b * N + t) * 3 + d;
    vv[d] = em * vb[idx] + dv[idx];
    xx[d] = xb[idx] + vv[d];
  }
  #pragma unroll
  for (int d = 0; d < 3; ++d) {
    red[t] = xx[d];
    __syncthreads();
    for (int s = 64; s > 0; s >>= 1) { if (t < s) red[t] += red[t + s]; __syncthreads(); }
    xx[d] -= red[0] * (1.0f / (float)N);
    __syncthreads();
    red[t] = vv[d];
    __syncthreads();
    for (int s = 64; s > 0; s >>= 1) { if (t < s) red[t] += red[t + s]; __syncthreads(); }
    vv[d] -= red[0] * (1.0f / (float)N);
    __syncthreads();
  }
  #pragma unroll
  for (int d = 0; d < 3; ++d) {
    int idx = (b * N + t) * 3 + d;
    xb[idx] = xx[d];
    vb[idx] = vv[d];
  }
  red[t] = m;
  __syncthreads();
  for (int s = 64; s > 0; s >>= 1) { if (t < s) red[t] += red[t + s]; __syncthreads(); }
  if (t == 0) sld[b] += 3.0f * red[0];
}

__global__ void k_out(const float* __restrict__ xw, const float* __restrict__ vw,
                      const float* __restrict__ sld, float* __restrict__ out) {
  int t = blockIdx.x * blockDim.x + threadIdx.x;
  if (t < B * N * 3) { out[t] = xw[t]; out[B * N * 3 + t] = vw[t]; }
  if (t < B) out[2 * B * N * 3 + t] = sld[t];
}

}  // namespace

extern "C" void kernel_launch(void* const* d_in, const int* in_sizes, int n_in,
                              void* d_out, int out_size, void* d_ws, size_t ws_size,
                              hipStream_t stream) {
  const float* in_h   = (const float*)d_in[0];
  const float* in_x   = (const float*)d_in[1];
  const float* in_v   = (const float*)d_in[2];
  const float* emb1_w = (const float*)d_in[3];
  const float* emb1_b = (const float*)d_in[4];
  const float* emb2_w = (const float*)d_in[5];
  const float* emb2_b = (const float*)d_in[6];
  const float* ein_w  = (const float*)d_in[7];
  const float* ein_b  = (const float*)d_in[8];
  const float* rbf_m  = (const float*)d_in[9];
  const float* rbf_b  = (const float*)d_in[10];
  const float* eo1w   = (const float*)d_in[11];
  const float* eo1b   = (const float*)d_in[12];
  const float* eo2w   = (const float*)d_in[13];
  const float* eo2b   = (const float*)d_in[14];
  const float* xmix   = (const float*)d_in[15];
  const float* p1w    = (const float*)d_in[16];
  const float* p1b    = (const float*)d_in[17];
  const float* p2w    = (const float*)d_in[18];
  const float* p2b    = (const float*)d_in[19];
  const float* semw   = (const float*)d_in[20];
  const float* semb   = (const float*)d_in[21];
  const float* n1w    = (const float*)d_in[22];
  const float* n1b    = (const float*)d_in[23];
  const float* n2w    = (const float*)d_in[24];
  const float* n2b    = (const float*)d_in[25];
  const float* v1w    = (const float*)d_in[26];
  const float* v1b    = (const float*)d_in[27];
  const float* v2w    = (const float*)d_in[28];
  const float* c1w    = (const float*)d_in[29];
  const float* c1b    = (const float*)d_in[30];
  const float* c2w    = (const float*)d_in[31];

  float* ws   = (float*)d_ws;
  float* h0   = ws;                 // BN*F
  float* hw   = h0 + BN * F;        // BN*F
  float* hkA0 = hw + BN * F;        // BN*K
  float* hkB0 = hkA0 + BN * K;
  float* e1A0 = hkB0 + BN * K;      // BN*F
  float* e1B0 = e1A0 + BN * F;
  float* hkA1 = e1B0 + BN * F;
  float* hkB1 = hkA1 + BN * K;
  float* e1A1 = hkB1 + BN * K;
  float* e1B1 = e1A1 + BN * F;
  float* uA   = e1B1 + BN * F;      // BN*F
  float* uB   = uA + BN * F;
  float* xw   = uB + BN * F;        // BN*3
  float* vw   = xw + BN * 3;
  float* dvb  = vw + BN * 3;
  float* mbuf = dvb + BN * 3;       // BN
  float* sld  = mbuf + BN;          // B

  k_init<<<6, 256, 0, stream>>>(in_x, in_v, xw, vw, sld);
  k_embed<<<BN, F, 0, stream>>>(in_h, emb1_w, emb1_b, emb2_w, emb2_b, h0);

  float* hkA[2] = {hkA0, hkA1};
  float* hkB[2] = {hkB0, hkB1};
  float* e1A[2] = {e1A0, e1A1};
  float* e1B[2] = {e1B0, e1B1};

  for (int dep = 0; dep < 2; ++dep) {
    for (int half = 0; half < 2; ++half) {
      int l = 2 * dep + half;
      float* xb = half ? vw : xw;
      float* vb = half ? xw : vw;
      const float* einw_l = ein_w + l * 2 * F * K;
      const float* einb_l = ein_b + l * K;
      const float* rbm_l  = rbf_m + l * K;
      const float* rbb_l  = rbf_b + l * K;
      const float* eo1w_l = eo1w + l * 179 * F;
      const float* eo1b_l = eo1b + l * F;
      const float* eo2w_l = eo2w + l * F * F;
      const float* eo2b_l = eo2b + l * F;
      const float* xmix_l = xmix + l * F * C;
      const float* p1w_l  = p1w + l * C * F;
      const float* p1b_l  = p1b + l * F;
      const float* p2w_l  = p2w + l * F * F;
      const float* p2b_l  = p2b + l * F;
      const float* semw_l = semw + l * F * H;
      const float* semb_l = semb + l * H;
      const float* n1w_l  = n1w + l * 384 * F;
      const float* n1b_l  = n1b + l * F;
      const float* n2w_l  = n2w + l * F * F;
      const float* n2b_l  = n2b + l * F;
      const float* v1w_l  = v1w + l * F * F;
      const float* v1b_l  = v1b + l * F;
      const float* v2w_l  = v2w + l * F;
      const float* c1w_l  = c1w + l * 2 * F * F;
      const float* c1b_l  = c1b + l * F;
      const float* c2w_l  = c2w + l * F;

      k_pre<<<BN, 256, 0, stream>>>(h0, hw, einw_l, eo1w_l, hkA[0], hkB[0], e1A[0], e1B[0]);
      // step 0: in set0 -> out set1 ; step 1: in set1 -> out set0 ; step 2: in set0, tail
      k_mp<1, 0><<<BN, 256, 0, stream>>>(hw, xb, hkA[0], hkB[0], e1A[0], e1B[0],
          einb_l, rbm_l, rbb_l, eo1w_l, eo1b_l, eo2w_l, eo2b_l, xmix_l,
          p1w_l, p1b_l, p2w_l, p2b_l, semw_l, semb_l, n1w_l, n1b_l, n2w_l, n2b_l,
          einw_l, hkA[1], hkB[1], e1A[1], e1B[1],
          c1w_l, v1w_l, v1b_l, v2w_l, uA, uB, mbuf);
      k_mp<1, 0><<<BN, 256, 0, stream>>>(hw, xb, hkA[1], hkB[1], e1A[1], e1B[1],
          einb_l, rbm_l, rbb_l, eo1w_l, eo1b_l, eo2w_l, eo2b_l, xmix_l,
          p1w_l, p1b_l, p2w_l, p2b_l, semw_l, semb_l, n1w_l, n1b_l, n2w_l, n2b_l,
          einw_l, hkA[0], hkB[0], e1A[0], e1B[0],
          c1w_l, v1w_l, v1b_l, v2w_l, uA, uB, mbuf);
      k_mp<0, 1><<<BN, 256, 0, stream>>>(hw, xb, hkA[0], hkB[0], e1A[0], e1B[0],
          einb_l, rbm_l, rbb_l, eo1w_l, eo1b_l, eo2w_l, eo2b_l, xmix_l,
          p1w_l, p1b_l, p2w_l, p2b_l, semw_l, semb_l, n1w_l, n1b_l, n2w_l, n2b_l,
          einw_l, hkA[1], hkB[1], e1A[1], e1B[1],
          c1w_l, v1w_l, v1b_l, v2w_l, uA, uB, mbuf);
      k_tail<<<BN, 256, 0, stream>>>(xb, uA, uB, c1b_l, c2w_l, dvb);
      k_fin<<<B, 128, 0, stream>>>(xb, vb, dvb, mbuf, sld);
    }
  }
  k_out<<<6, 256, 0, stream>>>(xw, vw, sld, (float*)d_out);
}

// Round 3
// 1245.986 us; speedup vs baseline: 1.9882x; 1.1240x over previous
//
#include <hip/hip_runtime.h>
#include <math.h>

namespace {

constexpr int B = 4, N = 128, FIN = 16, F = 64, H = 4, K = 50, C = 256;
constexpr int BN = B * N;
constexpr float EPS = 1e-5f;

__device__ __forceinline__ float silu_f(float x) { return x / (1.0f + __expf(-x)); }
__device__ __forceinline__ float tanh_f(float x) { return 1.0f - 2.0f / (__expf(2.0f * x) + 1.0f); }

__global__ void k_init(const float* __restrict__ x, const float* __restrict__ v,
                       float* __restrict__ xw, float* __restrict__ vw, float* __restrict__ sld) {
  int t = blockIdx.x * blockDim.x + threadIdx.x;
  if (t < B * N * 3) { xw[t] = x[t]; vw[t] = v[t]; }
  if (t < B) sld[t] = 0.0f;
}

__global__ __launch_bounds__(F) void k_embed(const float* __restrict__ hin,
    const float* __restrict__ w1, const float* __restrict__ b1,
    const float* __restrict__ w2, const float* __restrict__ b2, float* __restrict__ h0) {
  int node = blockIdx.x, f = threadIdx.x;
  __shared__ float t1[F];
  float acc = b1[f];
  #pragma unroll
  for (int r = 0; r < FIN; ++r) acc += hin[node * FIN + r] * w1[r * F + f];
  t1[f] = silu_f(acc);
  __syncthreads();
  float a0 = b2[f], a1 = 0.f, a2 = 0.f, a3 = 0.f;
  #pragma unroll
  for (int r = 0; r < F; r += 4) {
    a0 += t1[r] * w2[r * F + f];
    a1 += t1[r + 1] * w2[(r + 1) * F + f];
    a2 += t1[r + 2] * w2[(r + 2) * F + f];
    a3 += t1[r + 3] * w2[(r + 3) * F + f];
  }
  h0[node * F + f] = (a0 + a1) + (a2 + a3);
}

// Per-node precomputation at flow start: hkA/hkB (edge_in halves), e1A/e1B (eo1 halves).
__global__ __launch_bounds__(256) void k_pre(const float* __restrict__ h0, float* __restrict__ hw,
    const float* __restrict__ ein_w, const float* __restrict__ eo1w,
    float* __restrict__ hkA, float* __restrict__ hkB,
    float* __restrict__ e1A, float* __restrict__ e1B) {
  int node = blockIdx.x, t = threadIdx.x;
  __shared__ float s_h[F];
  if (t < F) s_h[t] = h0[node * F + t];
  __syncthreads();
  if (t < F) hw[node * F + t] = s_h[t];
  if (t < 228) {
    float a0 = 0.f, a1 = 0.f, a2 = 0.f, a3 = 0.f;
    if (t < 50) { int k = t;
      #pragma unroll
      for (int r = 0; r < F; r += 4) {
        a0 += s_h[r] * ein_w[r * K + k];       a1 += s_h[r + 1] * ein_w[(r + 1) * K + k];
        a2 += s_h[r + 2] * ein_w[(r + 2) * K + k]; a3 += s_h[r + 3] * ein_w[(r + 3) * K + k];
      }
      hkA[node * K + k] = (a0 + a1) + (a2 + a3);
    } else if (t < 100) { int k = t - 50;
      #pragma unroll
      for (int r = 0; r < F; r += 4) {
        a0 += s_h[r] * ein_w[(F + r) * K + k];       a1 += s_h[r + 1] * ein_w[(F + r + 1) * K + k];
        a2 += s_h[r + 2] * ein_w[(F + r + 2) * K + k]; a3 += s_h[r + 3] * ein_w[(F + r + 3) * K + k];
      }
      hkB[node * K + k] = (a0 + a1) + (a2 + a3);
    } else if (t < 164) { int c = t - 100;
      #pragma unroll
      for (int r = 0; r < F; r += 4) {
        a0 += s_h[r] * eo1w[r * F + c];       a1 += s_h[r + 1] * eo1w[(r + 1) * F + c];
        a2 += s_h[r + 2] * eo1w[(r + 2) * F + c]; a3 += s_h[r + 3] * eo1w[(r + 3) * F + c];
      }
      e1A[node * F + c] = (a0 + a1) + (a2 + a3);
    } else { int c = t - 164;
      #pragma unroll
      for (int r = 0; r < F; r += 4) {
        a0 += s_h[r] * eo1w[(F + r) * F + c];       a1 += s_h[r + 1] * eo1w[(F + r + 1) * F + c];
        a2 += s_h[r + 2] * eo1w[(F + r + 2) * F + c]; a3 += s_h[r + 3] * eo1w[(F + r + 3) * F + c];
      }
      e1B[node * F + c] = (a0 + a1) + (a2 + a3);
    }
  }
}

// Fused message-passing step for one (b,i): 256 threads / 4 waves.
// he is stored TRANSPOSED (he_T[r][j], pad 132) so the big coeff GEMM can be
// register-tiled (16j x 4c per thread, xmix streamed coalesced from L2) raising
// the FMA:LDS-instr ratio from 4:1 to ~13:1. h_e reads he_T j-contiguously,
// logits read conflict-free columns.
template<int PRE, int TAIL>
__global__ __launch_bounds__(256, 2) void k_mp(
    float* __restrict__ hw, const float* __restrict__ xp,
    const float* __restrict__ hkA_in, const float* __restrict__ hkB_in,
    const float* __restrict__ e1A_in, const float* __restrict__ e1B_in,
    const float* __restrict__ ein_b, const float* __restrict__ rbf_m, const float* __restrict__ rbf_b,
    const float* __restrict__ eo1w, const float* __restrict__ eo1b,
    const float* __restrict__ eo2w, const float* __restrict__ eo2b,
    const float* __restrict__ xmix,
    const float* __restrict__ p1w, const float* __restrict__ p1b,
    const float* __restrict__ p2w, const float* __restrict__ p2b,
    const float* __restrict__ semw, const float* __restrict__ semb,
    const float* __restrict__ n1w, const float* __restrict__ n1b,
    const float* __restrict__ n2w, const float* __restrict__ n2b,
    const float* __restrict__ ein_w,
    float* __restrict__ hkA_out, float* __restrict__ hkB_out,
    float* __restrict__ e1A_out, float* __restrict__ e1B_out,
    const float* __restrict__ c1w, const float* __restrict__ v1w, const float* __restrict__ v1b,
    const float* __restrict__ v2w,
    float* __restrict__ uA, float* __restrict__ uB, float* __restrict__ mbuf) {
  int blk = blockIdx.x, b = blk >> 7, i = blk & 127;
  int t = threadIdx.x, w = t >> 6, lane = t & 63;
  int bN = b * N;
  constexpr float invN = 1.0f / (float)N;

  __shared__ __align__(16) float s_heT[64 * 132];  // he transposed [r][j], pad 132
  __shared__ __align__(16) float s_union[4352];    // t1buf (edge) / post-edge scratch
  __shared__ __align__(16) float4 s_dxn[N];        // (dx0,dx1,dx2,dn)
  __shared__ float s_inv[N];                       // 1/(dn+EPS)
  __shared__ float s_xpos[N * 3];
  __shared__ float s_hi[F];
  __shared__ float s_zkbase[K];
  __shared__ float s_e1base[F];
  __shared__ __align__(16) float s_zk[4][56];
  __shared__ float s_cat[384];
  __shared__ float s_wred[8];
  __shared__ float s_wsum[8];

  float* t1buf   = s_union;          // [64][68]  (edge phase only)
  float* s_cpart = s_union;          // [4][256][3] = 3072 floats
  float* s_attT  = s_union + 3072;   // [4][128]
  float* s_hcin  = s_union + 3584;   // [256]
  float* s_part  = s_union + 3840;   // [4][64]
  float* s_vec   = s_union + 4096;   // [64]
  float* s_hnew  = s_union + 4160;   // [64]

  // ---- staging ----
  for (int idx = t; idx < N * 3; idx += 256) s_xpos[idx] = xp[bN * 3 + idx];
  if (t < F) s_hi[t] = hw[(bN + i) * F + t];
  if (t < K) s_zkbase[t] = hkA_in[(bN + i) * K + t] + ein_b[t];
  if (t >= 64 && t < 128) s_e1base[t - 64] = e1A_in[(bN + i) * F + (t - 64)] + eo1b[t - 64];
  if (lane >= 50 && lane < 56) s_zk[w][lane] = 0.f;  // float4 pad
  __syncthreads();
  if (t < N) {
    float dx0 = s_xpos[i * 3 + 0] - s_xpos[t * 3 + 0];
    float dx1 = s_xpos[i * 3 + 1] - s_xpos[t * 3 + 1];
    float dx2 = s_xpos[i * 3 + 2] - s_xpos[t * 3 + 2];
    float dn = sqrtf(dx0 * dx0 + dx1 * dx1 + dx2 * dx2 + EPS * EPS);
    s_dxn[t] = make_float4(dx0, dx1, dx2, dn);
    s_inv[t] = 1.0f / (dn + EPS);
  }
  __syncthreads();

  float rbm = 0.f, rbb = 0.f;
  if (lane < K) { rbm = rbf_m[lane]; rbb = rbf_b[lane]; }

  // ---- edge phase: waves own contiguous 16-j ranges, two 64-j halves ----
  for (int half = 0; half < 2; ++half) {
    int jbase = half * 64 + w * 16;
    {  // sub-pass A: t1 rows (only wk live)
      float wk[52];
      #pragma unroll
      for (int k = 0; k < 50; ++k) wk[k] = eo1w[(128 + k) * F + lane];
      wk[50] = 0.f; wk[51] = 0.f;
      float w1d = eo1w[178 * F + lane];
      float nhk = (lane < K) ? hkB_in[(bN + jbase) * K + lane] : 0.f;
      float ne1 = e1B_in[(bN + jbase) * F + lane];
      for (int jj = 0; jj < 16; ++jj) {
        int j = jbase + jj;
        float hk = nhk, e1v = ne1;
        if (jj < 15) {
          nhk = (lane < K) ? hkB_in[(bN + j + 1) * K + lane] : 0.f;
          ne1 = e1B_in[(bN + j + 1) * F + lane];
        }
        float dn = s_dxn[j].w;
        if (lane < K) {
          float hkf = s_zkbase[lane] + hk;
          float e = __expf(-dn) - rbm;
          s_zk[w][lane] = __expf(-rbb * e * e) * hkf;
        }
        float ac0 = s_e1base[lane] + e1v + dn * w1d, ac1 = 0.f, ac2 = 0.f, ac3 = 0.f;
        const float4* z4 = (const float4*)(&s_zk[w][0]);
        #pragma unroll
        for (int k4 = 0; k4 < 13; ++k4) {
          float4 z = z4[k4];
          ac0 += z.x * wk[4 * k4];     ac1 += z.y * wk[4 * k4 + 1];
          ac2 += z.z * wk[4 * k4 + 2]; ac3 += z.w * wk[4 * k4 + 3];
        }
        t1buf[(j & 63) * 68 + lane] = silu_f((ac0 + ac1) + (ac2 + ac3));
      }
    }
    // same-wave rows -> no barrier needed
    {  // sub-pass B: he = t1 @ eo2 (only er live), b128-packed writes into he_T
      float er[64];
      #pragma unroll
      for (int r = 0; r < F; ++r) er[r] = eo2w[r * F + lane];
      float b2 = eo2b[lane];
      for (int jj4 = 0; jj4 < 4; ++jj4) {
        float hv[4];
        #pragma unroll
        for (int q = 0; q < 4; ++q) {
          int row = ((jbase + jj4 * 4 + q) & 63) * 68;
          const float4* t4 = (const float4*)(&t1buf[row]);
          float ac0 = b2, ac1 = 0.f, ac2 = 0.f, ac3 = 0.f;
          #pragma unroll
          for (int r4 = 0; r4 < 16; ++r4) {
            float4 tt = t4[r4];
            ac0 += tt.x * er[4 * r4];     ac1 += tt.y * er[4 * r4 + 1];
            ac2 += tt.z * er[4 * r4 + 2]; ac3 += tt.w * er[4 * r4 + 3];
          }
          hv[q] = (ac0 + ac1) + (ac2 + ac3);
        }
        *(float4*)(&s_heT[lane * 132 + jbase + jj4 * 4]) = make_float4(hv[0], hv[1], hv[2], hv[3]);
      }
    }
  }
  __syncthreads();  // he_T complete; t1buf dead -> union becomes scratch

  // ---- coeff phase: register-tiled 16j x 4c, 2 passes; xmix streamed from L2 ----
  {
    int c0 = 4 * (t & 63);
    float4 aX = make_float4(0.f, 0.f, 0.f, 0.f);
    float4 aY = make_float4(0.f, 0.f, 0.f, 0.f);
    float4 aZ = make_float4(0.f, 0.f, 0.f, 0.f);
    #pragma unroll
    for (int p = 0; p < 2; ++p) {
      int j0 = w * 32 + p * 16;
      float4 cacc[16];
      #pragma unroll
      for (int jj = 0; jj < 16; ++jj) cacc[jj] = make_float4(0.f, 0.f, 0.f, 0.f);
      for (int r = 0; r < 64; ++r) {
        float4 xm4 = *(const float4*)(&xmix[r * C + c0]);
        const float4* hb = (const float4*)(&s_heT[r * 132 + j0]);
        float4 h0v = hb[0], h1v = hb[1], h2v = hb[2], h3v = hb[3];
#define CSTEP(idx, hval) \
        cacc[idx].x += (hval) * xm4.x; cacc[idx].y += (hval) * xm4.y; \
        cacc[idx].z += (hval) * xm4.z; cacc[idx].w += (hval) * xm4.w;
        CSTEP(0, h0v.x)  CSTEP(1, h0v.y)  CSTEP(2, h0v.z)  CSTEP(3, h0v.w)
        CSTEP(4, h1v.x)  CSTEP(5, h1v.y)  CSTEP(6, h1v.z)  CSTEP(7, h1v.w)
        CSTEP(8, h2v.x)  CSTEP(9, h2v.y)  CSTEP(10, h2v.z) CSTEP(11, h2v.w)
        CSTEP(12, h3v.x) CSTEP(13, h3v.y) CSTEP(14, h3v.z) CSTEP(15, h3v.w)
#undef CSTEP
      }
      #pragma unroll
      for (int jj = 0; jj < 16; ++jj) {
        int j = j0 + jj;
        float4 dq = s_dxn[j];
        float inv = s_inv[j];
        float s0 = tanh_f(cacc[jj].x) * inv;
        float s1 = tanh_f(cacc[jj].y) * inv;
        float s2 = tanh_f(cacc[jj].z) * inv;
        float s3 = tanh_f(cacc[jj].w) * inv;
        aX.x += dq.x * s0; aY.x += dq.y * s0; aZ.x += dq.z * s0;
        aX.y += dq.x * s1; aY.y += dq.y * s1; aZ.y += dq.z * s1;
        aX.z += dq.x * s2; aY.z += dq.y * s2; aZ.z += dq.z * s2;
        aX.w += dq.x * s3; aY.w += dq.y * s3; aZ.w += dq.z * s3;
      }
    }
    int cb = w * 768 + c0 * 3;
    s_cpart[cb + 0] = aX.x; s_cpart[cb + 1] = aY.x; s_cpart[cb + 2]  = aZ.x;
    s_cpart[cb + 3] = aX.y; s_cpart[cb + 4] = aY.y; s_cpart[cb + 5]  = aZ.y;
    s_cpart[cb + 6] = aX.z; s_cpart[cb + 7] = aY.z; s_cpart[cb + 8]  = aZ.z;
    s_cpart[cb + 9] = aX.w; s_cpart[cb + 10] = aY.w; s_cpart[cb + 11] = aZ.w;
  }

  // ---- attention phase: thread t -> j = t&127, heads {2g,2g+1}; he_T column reads ----
  {
    int g = t >> 7, j = t & 127;
    int ha = 2 * g, hb_ = ha + 1;
    float l0a = 0.f, l0b = 0.f, l1a = 0.f, l1b = 0.f;
    #pragma unroll 8
    for (int r = 0; r < 64; r += 2) {
      float hv0 = s_heT[r * 132 + j];
      float hv1 = s_heT[(r + 1) * 132 + j];
      l0a += hv0 * semw[r * H + ha];       l1a += hv0 * semw[r * H + hb_];
      l0b += hv1 * semw[(r + 1) * H + ha]; l1b += hv1 * semw[(r + 1) * H + hb_];
    }
    float l0 = semb[ha] + l0a + l0b;
    float l1 = semb[hb_] + l1a + l1b;
    l0 = l0 > 0.f ? l0 : 2.0f * (__expf(0.5f * l0) - 1.0f);  // celu alpha=2
    l1 = l1 > 0.f ? l1 : 2.0f * (__expf(0.5f * l1) - 1.0f);
    if (j == i) { l0 -= 1e5f; l1 -= 1e5f; }
    float m0 = l0, m1 = l1;
    #pragma unroll
    for (int off = 32; off > 0; off >>= 1) {
      m0 = fmaxf(m0, __shfl_xor(m0, off));
      m1 = fmaxf(m1, __shfl_xor(m1, off));
    }
    if (lane == 0) { s_wred[w * 2] = m0; s_wred[w * 2 + 1] = m1; }
    __syncthreads();   // also publishes s_cpart
    {  // hcin combine rides in this gap
      int c = t;
      float q0 = (s_cpart[c * 3 + 0] + s_cpart[768 + c * 3 + 0] + s_cpart[1536 + c * 3 + 0] + s_cpart[2304 + c * 3 + 0]) * invN;
      float q1 = (s_cpart[c * 3 + 1] + s_cpart[768 + c * 3 + 1] + s_cpart[1536 + c * 3 + 1] + s_cpart[2304 + c * 3 + 1]) * invN;
      float q2 = (s_cpart[c * 3 + 2] + s_cpart[768 + c * 3 + 2] + s_cpart[1536 + c * 3 + 2] + s_cpart[2304 + c * 3 + 2]) * invN;
      s_hcin[c] = q0 * q0 + q1 * q1 + q2 * q2;
    }
    int pw = w ^ 1;  // partner wave covers the other 64 j's of the same heads
    float M0 = fmaxf(s_wred[w * 2], s_wred[pw * 2]);
    float M1 = fmaxf(s_wred[w * 2 + 1], s_wred[pw * 2 + 1]);
    float e0 = __expf(l0 - M0), e1 = __expf(l1 - M1);
    float sm0 = e0, sm1 = e1;
    #pragma unroll
    for (int off = 32; off > 0; off >>= 1) {
      sm0 += __shfl_xor(sm0, off);
      sm1 += __shfl_xor(sm1, off);
    }
    if (lane == 0) { s_wsum[w * 2] = sm0; s_wsum[w * 2 + 1] = sm1; }
    __syncthreads();
    float S0 = s_wsum[w * 2] + s_wsum[pw * 2];
    float S1 = s_wsum[w * 2 + 1] + s_wsum[pw * 2 + 1];
    s_attT[ha * 128 + j] = e0 / S0;
    s_attT[hb_ * 128 + j] = e1 / S1;
  }
  __syncthreads();

  // ---- h_e phase: thread t -> (f = t>>2, head = t&3); j-contiguous b128 reads ----
  {
    int f = t >> 2, hh = t & 3;
    const float4* hr = (const float4*)(&s_heT[f * 132]);
    const float4* ar = (const float4*)(&s_attT[hh * 128]);
    float ac0 = 0.f, ac1 = 0.f, ac2 = 0.f, ac3 = 0.f;
    #pragma unroll 8
    for (int jg = 0; jg < 32; ++jg) {
      float4 hv = hr[jg];
      float4 av = ar[jg];
      ac0 += hv.x * av.x; ac1 += hv.y * av.y; ac2 += hv.z * av.z; ac3 += hv.w * av.w;
    }
    s_cat[64 + t] = (ac0 + ac1) + (ac2 + ac3);   // h_e slot of concat
  }

  // ---- node phase ----
  {
    int c0 = w * 64;
    float a0 = 0.f, a1 = 0.f, a2 = 0.f, a3 = 0.f;
    #pragma unroll 8
    for (int cc = 0; cc < 64; cc += 4) {
      a0 += s_hcin[c0 + cc] * p1w[(c0 + cc) * F + lane];
      a1 += s_hcin[c0 + cc + 1] * p1w[(c0 + cc + 1) * F + lane];
      a2 += s_hcin[c0 + cc + 2] * p1w[(c0 + cc + 2) * F + lane];
      a3 += s_hcin[c0 + cc + 3] * p1w[(c0 + cc + 3) * F + lane];
    }
    s_part[w * 64 + lane] = (a0 + a1) + (a2 + a3);
  }
  __syncthreads();
  if (t < F) s_vec[t] = silu_f(s_part[t] + s_part[64 + t] + s_part[128 + t] + s_part[192 + t] + p1b[t]);
  __syncthreads();
  if (t < F) {
    float a0 = p2b[t], a1 = 0.f, a2 = 0.f, a3 = 0.f;
    #pragma unroll 8
    for (int r = 0; r < F; r += 4) {
      a0 += s_vec[r] * p2w[r * F + t];
      a1 += s_vec[r + 1] * p2w[(r + 1) * F + t];
      a2 += s_vec[r + 2] * p2w[(r + 2) * F + t];
      a3 += s_vec[r + 3] * p2w[(r + 3) * F + t];
    }
    s_cat[t] = s_hi[t];
    s_cat[320 + t] = silu_f((a0 + a1) + (a2 + a3));
  }
  __syncthreads();
  {
    int r0 = w * 96;
    float a0 = 0.f, a1 = 0.f, a2 = 0.f, a3 = 0.f;
    #pragma unroll 8
    for (int rr = 0; rr < 96; rr += 4) {
      a0 += s_cat[r0 + rr] * n1w[(r0 + rr) * F + lane];
      a1 += s_cat[r0 + rr + 1] * n1w[(r0 + rr + 1) * F + lane];
      a2 += s_cat[r0 + rr + 2] * n1w[(r0 + rr + 2) * F + lane];
      a3 += s_cat[r0 + rr + 3] * n1w[(r0 + rr + 3) * F + lane];
    }
    s_part[w * 64 + lane] = (a0 + a1) + (a2 + a3);
  }
  __syncthreads();
  if (t < F) s_vec[t] = silu_f(s_part[t] + s_part[64 + t] + s_part[128 + t] + s_part[192 + t] + n1b[t]);
  __syncthreads();
  if (t < F) {
    float a0 = n2b[t], a1 = 0.f, a2 = 0.f, a3 = 0.f;
    #pragma unroll 8
    for (int r = 0; r < F; r += 4) {
      a0 += s_vec[r] * n2w[r * F + t];
      a1 += s_vec[r + 1] * n2w[(r + 1) * F + t];
      a2 += s_vec[r + 2] * n2w[(r + 2) * F + t];
      a3 += s_vec[r + 3] * n2w[(r + 3) * F + t];
    }
    float hn = s_hi[t] + silu_f((a0 + a1) + (a2 + a3));
    s_hnew[t] = hn;
    hw[(bN + i) * F + t] = hn;
  }
  __syncthreads();

  if (PRE) {  // next-step node precomp from updated h
    if (t < 228) {
      float a0 = 0.f, a1 = 0.f, a2 = 0.f, a3 = 0.f;
      if (t < 50) { int k = t;
        #pragma unroll
        for (int r = 0; r < F; r += 4) {
          a0 += s_hnew[r] * ein_w[r * K + k];       a1 += s_hnew[r + 1] * ein_w[(r + 1) * K + k];
          a2 += s_hnew[r + 2] * ein_w[(r + 2) * K + k]; a3 += s_hnew[r + 3] * ein_w[(r + 3) * K + k];
        }
        hkA_out[(bN + i) * K + k] = (a0 + a1) + (a2 + a3);
      } else if (t < 100) { int k = t - 50;
        #pragma unroll
        for (int r = 0; r < F; r += 4) {
          a0 += s_hnew[r] * ein_w[(F + r) * K + k];       a1 += s_hnew[r + 1] * ein_w[(F + r + 1) * K + k];
          a2 += s_hnew[r + 2] * ein_w[(F + r + 2) * K + k]; a3 += s_hnew[r + 3] * ein_w[(F + r + 3) * K + k];
        }
        hkB_out[(bN + i) * K + k] = (a0 + a1) + (a2 + a3);
      } else if (t < 164) { int c = t - 100;
        #pragma unroll
        for (int r = 0; r < F; r += 4) {
          a0 += s_hnew[r] * eo1w[r * F + c];       a1 += s_hnew[r + 1] * eo1w[(r + 1) * F + c];
          a2 += s_hnew[r + 2] * eo1w[(r + 2) * F + c]; a3 += s_hnew[r + 3] * eo1w[(r + 3) * F + c];
        }
        e1A_out[(bN + i) * F + c] = (a0 + a1) + (a2 + a3);
      } else { int c = t - 164;
        #pragma unroll
        for (int r = 0; r < F; r += 4) {
          a0 += s_hnew[r] * eo1w[(F + r) * F + c];       a1 += s_hnew[r + 1] * eo1w[(F + r + 1) * F + c];
          a2 += s_hnew[r + 2] * eo1w[(F + r + 2) * F + c]; a3 += s_hnew[r + 3] * eo1w[(F + r + 3) * F + c];
        }
        e1B_out[(bN + i) * F + c] = (a0 + a1) + (a2 + a3);
      }
    }
  }
  if (TAIL) {  // coord1 halves + vel scalar m for the flow tail
    if (w == 0) {
      float a0 = 0.f, a1 = 0.f, a2 = 0.f, a3 = 0.f;
      #pragma unroll
      for (int r = 0; r < F; r += 4) {
        a0 += s_hnew[r] * c1w[r * F + lane];       a1 += s_hnew[r + 1] * c1w[(r + 1) * F + lane];
        a2 += s_hnew[r + 2] * c1w[(r + 2) * F + lane]; a3 += s_hnew[r + 3] * c1w[(r + 3) * F + lane];
      }
      uA[(bN + i) * F + lane] = (a0 + a1) + (a2 + a3);
    } else if (w == 1) {
      float a0 = 0.f, a1 = 0.f, a2 = 0.f, a3 = 0.f;
      #pragma unroll
      for (int r = 0; r < F; r += 4) {
        a0 += s_hnew[r] * c1w[(F + r) * F + lane];       a1 += s_hnew[r + 1] * c1w[(F + r + 1) * F + lane];
        a2 += s_hnew[r + 2] * c1w[(F + r + 2) * F + lane]; a3 += s_hnew[r + 3] * c1w[(F + r + 3) * F + lane];
      }
      uB[(bN + i) * F + lane] = (a0 + a1) + (a2 + a3);
    } else if (w == 2) {
      float a0 = v1b[lane], a1 = 0.f, a2 = 0.f, a3 = 0.f;
      #pragma unroll
      for (int r = 0; r < F; r += 4) {
        a0 += s_hnew[r] * v1w[r * F + lane];       a1 += s_hnew[r + 1] * v1w[(r + 1) * F + lane];
        a2 += s_hnew[r + 2] * v1w[(r + 2) * F + lane]; a3 += s_hnew[r + 3] * v1w[(r + 3) * F + lane];
      }
      float tv = silu_f((a0 + a1) + (a2 + a3)) * v2w[lane];
      #pragma unroll
      for (int off = 32; off > 0; off >>= 1) tv += __shfl_down(tv, off);
      if (lane == 0) mbuf[bN + i] = tv;
    }
  }
}

// delta_v[b,i] = (1/N) sum_j (coord2 . silu(uA_i + uB_j + b)) * (x_i - x_j)
__global__ __launch_bounds__(256) void k_tail(const float* __restrict__ xb,
    const float* __restrict__ uA, const float* __restrict__ uB,
    const float* __restrict__ c1b, const float* __restrict__ c2w,
    float* __restrict__ dv) {
  int blk = blockIdx.x, b = blk >> 7, i = blk & 127;
  int t = threadIdx.x, w = t >> 6, lane = t & 63;
  __shared__ float s_xpos[N * 3];
  __shared__ float s_uAi[F];
  __shared__ float s_acc[4][3];
  for (int idx = t; idx < N * 3; idx += 256) s_xpos[idx] = xb[b * N * 3 + idx];
  if (t < F) s_uAi[t] = uA[(b * N + i) * F + t];
  __syncthreads();
  float xi0 = s_xpos[i * 3 + 0], xi1 = s_xpos[i * 3 + 1], xi2 = s_xpos[i * 3 + 2];
  float base = s_uAi[lane] + c1b[lane];
  float c2v = c2w[lane];
  float a0 = 0.f, a1 = 0.f, a2 = 0.f;
  for (int jj = 0; jj < 32; ++jj) {
    int j = w + 4 * jj;
    float tv = silu_f(base + uB[(b * N + j) * F + lane]) * c2v;
    #pragma unroll
    for (int off = 32; off > 0; off >>= 1) tv += __shfl_down(tv, off);
    if (lane == 0) {
      float dx0 = xi0 - s_xpos[j * 3 + 0];
      float dx1 = xi1 - s_xpos[j * 3 + 1];
      float dx2 = xi2 - s_xpos[j * 3 + 2];
      a0 += tv * dx0; a1 += tv * dx1; a2 += tv * dx2;
    }
  }
  if (lane == 0) { s_acc[w][0] = a0; s_acc[w][1] = a1; s_acc[w][2] = a2; }
  __syncthreads();
  if (t < 3) {
    float s = s_acc[0][t] + s_acc[1][t] + s_acc[2][t] + s_acc[3][t];
    dv[(b * N + i) * 3 + t] = s * (1.0f / (float)N);
  }
}

// apply v' = exp(m)*v + dv, x' = x + v'; center x and v; sld += 3*sum(m). One block per batch.
__global__ __launch_bounds__(128) void k_fin(float* __restrict__ xb, float* __restrict__ vb,
    const float* __restrict__ dv, const float* __restrict__ mbuf, float* __restrict__ sld) {
  int b = blockIdx.x, t = threadIdx.x;
  __shared__ float red[N];
  float m = mbuf[b * N + t];
  float em = __expf(m);
  float vv[3], xx[3];
  #pragma unroll
  for (int d = 0; d < 3; ++d) {
    int idx = (b * N + t) * 3 + d;
    vv[d] = em * vb[idx] + dv[idx];
    xx[d] = xb[idx] + vv[d];
  }
  #pragma unroll
  for (int d = 0; d < 3; ++d) {
    red[t] = xx[d];
    __syncthreads();
    for (int s = 64; s > 0; s >>= 1) { if (t < s) red[t] += red[t + s]; __syncthreads(); }
    xx[d] -= red[0] * (1.0f / (float)N);
    __syncthreads();
    red[t] = vv[d];
    __syncthreads();
    for (int s = 64; s > 0; s >>= 1) { if (t < s) red[t] += red[t + s]; __syncthreads(); }
    vv[d] -= red[0] * (1.0f / (float)N);
    __syncthreads();
  }
  #pragma unroll
  for (int d = 0; d < 3; ++d) {
    int idx = (b * N + t) * 3 + d;
    xb[idx] = xx[d];
    vb[idx] = vv[d];
  }
  red[t] = m;
  __syncthreads();
  for (int s = 64; s > 0; s >>= 1) { if (t < s) red[t] += red[t + s]; __syncthreads(); }
  if (t == 0) sld[b] += 3.0f * red[0];
}

__global__ void k_out(const float* __restrict__ xw, const float* __restrict__ vw,
                      const float* __restrict__ sld, float* __restrict__ out) {
  int t = blockIdx.x * blockDim.x + threadIdx.x;
  if (t < B * N * 3) { out[t] = xw[t]; out[B * N * 3 + t] = vw[t]; }
  if (t < B) out[2 * B * N * 3 + t] = sld[t];
}

}  // namespace

extern "C" void kernel_launch(void* const* d_in, const int* in_sizes, int n_in,
                              void* d_out, int out_size, void* d_ws, size_t ws_size,
                              hipStream_t stream) {
  const float* in_h   = (const float*)d_in[0];
  const float* in_x   = (const float*)d_in[1];
  const float* in_v   = (const float*)d_in[2];
  const float* emb1_w = (const float*)d_in[3];
  const float* emb1_b = (const float*)d_in[4];
  const float* emb2_w = (const float*)d_in[5];
  const float* emb2_b = (const float*)d_in[6];
  const float* ein_w  = (const float*)d_in[7];
  const float* ein_b  = (const float*)d_in[8];
  const float* rbf_m  = (const float*)d_in[9];
  const float* rbf_b  = (const float*)d_in[10];
  const float* eo1w   = (const float*)d_in[11];
  const float* eo1b   = (const float*)d_in[12];
  const float* eo2w   = (const float*)d_in[13];
  const float* eo2b   = (const float*)d_in[14];
  const float* xmix   = (const float*)d_in[15];
  const float* p1w    = (const float*)d_in[16];
  const float* p1b    = (const float*)d_in[17];
  const float* p2w    = (const float*)d_in[18];
  const float* p2b    = (const float*)d_in[19];
  const float* semw   = (const float*)d_in[20];
  const float* semb   = (const float*)d_in[21];
  const float* n1w    = (const float*)d_in[22];
  const float* n1b    = (const float*)d_in[23];
  const float* n2w    = (const float*)d_in[24];
  const float* n2b    = (const float*)d_in[25];
  const float* v1w    = (const float*)d_in[26];
  const float* v1b    = (const float*)d_in[27];
  const float* v2w    = (const float*)d_in[28];
  const float* c1w    = (const float*)d_in[29];
  const float* c1b    = (const float*)d_in[30];
  const float* c2w    = (const float*)d_in[31];

  float* ws   = (float*)d_ws;
  float* h0   = ws;                 // BN*F
  float* hw   = h0 + BN * F;        // BN*F
  float* hkA0 = hw + BN * F;        // BN*K
  float* hkB0 = hkA0 + BN * K;
  float* e1A0 = hkB0 + BN * K;      // BN*F
  float* e1B0 = e1A0 + BN * F;
  float* hkA1 = e1B0 + BN * F;
  float* hkB1 = hkA1 + BN * K;
  float* e1A1 = hkB1 + BN * K;
  float* e1B1 = e1A1 + BN * F;
  float* uA   = e1B1 + BN * F;      // BN*F
  float* uB   = uA + BN * F;
  float* xw   = uB + BN * F;        // BN*3
  float* vw   = xw + BN * 3;
  float* dvb  = vw + BN * 3;
  float* mbuf = dvb + BN * 3;       // BN
  float* sld  = mbuf + BN;          // B

  k_init<<<6, 256, 0, stream>>>(in_x, in_v, xw, vw, sld);
  k_embed<<<BN, F, 0, stream>>>(in_h, emb1_w, emb1_b, emb2_w, emb2_b, h0);

  float* hkA[2] = {hkA0, hkA1};
  float* hkB[2] = {hkB0, hkB1};
  float* e1A[2] = {e1A0, e1A1};
  float* e1B[2] = {e1B0, e1B1};

  for (int dep = 0; dep < 2; ++dep) {
    for (int half = 0; half < 2; ++half) {
      int l = 2 * dep + half;
      float* xb = half ? vw : xw;
      float* vb = half ? xw : vw;
      const float* einw_l = ein_w + l * 2 * F * K;
      const float* einb_l = ein_b + l * K;
      const float* rbm_l  = rbf_m + l * K;
      const float* rbb_l  = rbf_b + l * K;
      const float* eo1w_l = eo1w + l * 179 * F;
      const float* eo1b_l = eo1b + l * F;
      const float* eo2w_l = eo2w + l * F * F;
      const float* eo2b_l = eo2b + l * F;
      const float* xmix_l = xmix + l * F * C;
      const float* p1w_l  = p1w + l * C * F;
      const float* p1b_l  = p1b + l * F;
      const float* p2w_l  = p2w + l * F * F;
      const float* p2b_l  = p2b + l * F;
      const float* semw_l = semw + l * F * H;
      const float* semb_l = semb + l * H;
      const float* n1w_l  = n1w + l * 384 * F;
      const float* n1b_l  = n1b + l * F;
      const float* n2w_l  = n2w + l * F * F;
      const float* n2b_l  = n2b + l * F;
      const float* v1w_l  = v1w + l * F * F;
      const float* v1b_l  = v1b + l * F;
      const float* v2w_l  = v2w + l * F;
      const float* c1w_l  = c1w + l * 2 * F * F;
      const float* c1b_l  = c1b + l * F;
      const float* c2w_l  = c2w + l * F;

      k_pre<<<BN, 256, 0, stream>>>(h0, hw, einw_l, eo1w_l, hkA[0], hkB[0], e1A[0], e1B[0]);
      // step 0: in set0 -> out set1 ; step 1: in set1 -> out set0 ; step 2: in set0, tail
      k_mp<1, 0><<<BN, 256, 0, stream>>>(hw, xb, hkA[0], hkB[0], e1A[0], e1B[0],
          einb_l, rbm_l, rbb_l, eo1w_l, eo1b_l, eo2w_l, eo2b_l, xmix_l,
          p1w_l, p1b_l, p2w_l, p2b_l, semw_l, semb_l, n1w_l, n1b_l, n2w_l, n2b_l,
          einw_l, hkA[1], hkB[1], e1A[1], e1B[1],
          c1w_l, v1w_l, v1b_l, v2w_l, uA, uB, mbuf);
      k_mp<1, 0><<<BN, 256, 0, stream>>>(hw, xb, hkA[1], hkB[1], e1A[1], e1B[1],
          einb_l, rbm_l, rbb_l, eo1w_l, eo1b_l, eo2w_l, eo2b_l, xmix_l,
          p1w_l, p1b_l, p2w_l, p2b_l, semw_l, semb_l, n1w_l, n1b_l, n2w_l, n2b_l,
          einw_l, hkA[0], hkB[0], e1A[0], e1B[0],
          c1w_l, v1w_l, v1b_l, v2w_l, uA, uB, mbuf);
      k_mp<0, 1><<<BN, 256, 0, stream>>>(hw, xb, hkA[0], hkB[0], e1A[0], e1B[0],
          einb_l, rbm_l, rbb_l, eo1w_l, eo1b_l, eo2w_l, eo2b_l, xmix_l,
          p1w_l, p1b_l, p2w_l, p2b_l, semw_l, semb_l, n1w_l, n1b_l, n2w_l, n2b_l,
          einw_l, hkA[1], hkB[1], e1A[1], e1B[1],
          c1w_l, v1w_l, v1b_l, v2w_l, uA, uB, mbuf);
      k_tail<<<BN, 256, 0, stream>>>(xb, uA, uB, c1b_l, c2w_l, dvb);
      k_fin<<<B, 128, 0, stream>>>(xb, vb, dvb, mbuf, sld);
    }
  }
  k_out<<<6, 256, 0, stream>>>(xw, vw, sld, (float*)d_out);
}

// Round 4
// 1212.868 us; speedup vs baseline: 2.0425x; 1.0273x over previous
//
#include <hip/hip_runtime.h>
#include <math.h>

namespace {

constexpr int B = 4, N = 128, FIN = 16, F = 64, H = 4, K = 50, C = 256;
constexpr int BN = B * N;
constexpr float EPS = 1e-5f;

__device__ __forceinline__ float silu_f(float x) { return x / (1.0f + __expf(-x)); }
__device__ __forceinline__ float tanh_f(float x) { return 1.0f - 2.0f / (__expf(2.0f * x) + 1.0f); }

__global__ void k_init(const float* __restrict__ x, const float* __restrict__ v,
                       float* __restrict__ xw, float* __restrict__ vw, float* __restrict__ sld) {
  int t = blockIdx.x * blockDim.x + threadIdx.x;
  if (t < B * N * 3) { xw[t] = x[t]; vw[t] = v[t]; }
  if (t < B) sld[t] = 0.0f;
}

__global__ __launch_bounds__(F) void k_embed(const float* __restrict__ hin,
    const float* __restrict__ w1, const float* __restrict__ b1,
    const float* __restrict__ w2, const float* __restrict__ b2, float* __restrict__ h0) {
  int node = blockIdx.x, f = threadIdx.x;
  __shared__ float t1[F];
  float acc = b1[f];
  #pragma unroll
  for (int r = 0; r < FIN; ++r) acc += hin[node * FIN + r] * w1[r * F + f];
  t1[f] = silu_f(acc);
  __syncthreads();
  float a0 = b2[f], a1 = 0.f, a2 = 0.f, a3 = 0.f;
  #pragma unroll
  for (int r = 0; r < F; r += 4) {
    a0 += t1[r] * w2[r * F + f];
    a1 += t1[r + 1] * w2[(r + 1) * F + f];
    a2 += t1[r + 2] * w2[(r + 2) * F + f];
    a3 += t1[r + 3] * w2[(r + 3) * F + f];
  }
  h0[node * F + f] = (a0 + a1) + (a2 + a3);
}

// Per-node precomputation at flow start: hkA/hkB (edge_in halves), e1A/e1B (eo1 halves).
__global__ __launch_bounds__(256) void k_pre(const float* __restrict__ h0, float* __restrict__ hw,
    const float* __restrict__ ein_w, const float* __restrict__ eo1w,
    float* __restrict__ hkA, float* __restrict__ hkB,
    float* __restrict__ e1A, float* __restrict__ e1B) {
  int node = blockIdx.x, t = threadIdx.x;
  __shared__ float s_h[F];
  if (t < F) s_h[t] = h0[node * F + t];
  __syncthreads();
  if (t < F) hw[node * F + t] = s_h[t];
  if (t < 228) {
    float a0 = 0.f, a1 = 0.f, a2 = 0.f, a3 = 0.f;
    if (t < 50) { int k = t;
      #pragma unroll
      for (int r = 0; r < F; r += 4) {
        a0 += s_h[r] * ein_w[r * K + k];       a1 += s_h[r + 1] * ein_w[(r + 1) * K + k];
        a2 += s_h[r + 2] * ein_w[(r + 2) * K + k]; a3 += s_h[r + 3] * ein_w[(r + 3) * K + k];
      }
      hkA[node * K + k] = (a0 + a1) + (a2 + a3);
    } else if (t < 100) { int k = t - 50;
      #pragma unroll
      for (int r = 0; r < F; r += 4) {
        a0 += s_h[r] * ein_w[(F + r) * K + k];       a1 += s_h[r + 1] * ein_w[(F + r + 1) * K + k];
        a2 += s_h[r + 2] * ein_w[(F + r + 2) * K + k]; a3 += s_h[r + 3] * ein_w[(F + r + 3) * K + k];
      }
      hkB[node * K + k] = (a0 + a1) + (a2 + a3);
    } else if (t < 164) { int c = t - 100;
      #pragma unroll
      for (int r = 0; r < F; r += 4) {
        a0 += s_h[r] * eo1w[r * F + c];       a1 += s_h[r + 1] * eo1w[(r + 1) * F + c];
        a2 += s_h[r + 2] * eo1w[(r + 2) * F + c]; a3 += s_h[r + 3] * eo1w[(r + 3) * F + c];
      }
      e1A[node * F + c] = (a0 + a1) + (a2 + a3);
    } else { int c = t - 164;
      #pragma unroll
      for (int r = 0; r < F; r += 4) {
        a0 += s_h[r] * eo1w[(F + r) * F + c];       a1 += s_h[r + 1] * eo1w[(F + r + 1) * F + c];
        a2 += s_h[r + 2] * eo1w[(F + r + 2) * F + c]; a3 += s_h[r + 3] * eo1w[(F + r + 3) * F + c];
      }
      e1B[node * F + c] = (a0 + a1) + (a2 + a3);
    }
  }
}

// Fused message-passing step for one (b,i): 256 threads / 4 waves.
// he stored TRANSPOSED (he_T[r][j], pad 132); coeff GEMM register-tiled 8j x 4c
// (32-reg accumulator tile -- fits the 128-VGPR allocation, no scratch spills),
// xmix streamed coalesced from L2.
template<int PRE, int TAIL>
__global__ __launch_bounds__(256, 2) void k_mp(
    float* __restrict__ hw, const float* __restrict__ xp,
    const float* __restrict__ hkA_in, const float* __restrict__ hkB_in,
    const float* __restrict__ e1A_in, const float* __restrict__ e1B_in,
    const float* __restrict__ ein_b, const float* __restrict__ rbf_m, const float* __restrict__ rbf_b,
    const float* __restrict__ eo1w, const float* __restrict__ eo1b,
    const float* __restrict__ eo2w, const float* __restrict__ eo2b,
    const float* __restrict__ xmix,
    const float* __restrict__ p1w, const float* __restrict__ p1b,
    const float* __restrict__ p2w, const float* __restrict__ p2b,
    const float* __restrict__ semw, const float* __restrict__ semb,
    const float* __restrict__ n1w, const float* __restrict__ n1b,
    const float* __restrict__ n2w, const float* __restrict__ n2b,
    const float* __restrict__ ein_w,
    float* __restrict__ hkA_out, float* __restrict__ hkB_out,
    float* __restrict__ e1A_out, float* __restrict__ e1B_out,
    const float* __restrict__ c1w, const float* __restrict__ v1w, const float* __restrict__ v1b,
    const float* __restrict__ v2w,
    float* __restrict__ uA, float* __restrict__ uB, float* __restrict__ mbuf) {
  int blk = blockIdx.x, b = blk >> 7, i = blk & 127;
  int t = threadIdx.x, w = t >> 6, lane = t & 63;
  int bN = b * N;
  constexpr float invN = 1.0f / (float)N;

  __shared__ __align__(16) float s_heT[64 * 132];  // he transposed [r][j], pad 132
  __shared__ __align__(16) float s_union[4352];    // t1buf (edge) / post-edge scratch
  __shared__ __align__(16) float4 s_dxn[N];        // (dx0,dx1,dx2,dn)
  __shared__ float s_inv[N];                       // 1/(dn+EPS)
  __shared__ float s_xpos[N * 3];
  __shared__ float s_hi[F];
  __shared__ float s_zkbase[K];
  __shared__ float s_e1base[F];
  __shared__ __align__(16) float s_zk[4][56];
  __shared__ float s_cat[384];
  __shared__ float s_wred[8];
  __shared__ float s_wsum[8];

  float* t1buf   = s_union;          // [64][68]  (edge phase only)
  float* s_cpart = s_union;          // [4][256][3] = 3072 floats
  float* s_attT  = s_union + 3072;   // [4][128]
  float* s_hcin  = s_union + 3584;   // [256]
  float* s_part  = s_union + 3840;   // [4][64]
  float* s_vec   = s_union + 4096;   // [64]
  float* s_hnew  = s_union + 4160;   // [64]

  // ---- staging ----
  for (int idx = t; idx < N * 3; idx += 256) s_xpos[idx] = xp[bN * 3 + idx];
  if (t < F) s_hi[t] = hw[(bN + i) * F + t];
  if (t < K) s_zkbase[t] = hkA_in[(bN + i) * K + t] + ein_b[t];
  if (t >= 64 && t < 128) s_e1base[t - 64] = e1A_in[(bN + i) * F + (t - 64)] + eo1b[t - 64];
  if (lane >= 50 && lane < 56) s_zk[w][lane] = 0.f;  // float4 pad
  __syncthreads();
  if (t < N) {
    float dx0 = s_xpos[i * 3 + 0] - s_xpos[t * 3 + 0];
    float dx1 = s_xpos[i * 3 + 1] - s_xpos[t * 3 + 1];
    float dx2 = s_xpos[i * 3 + 2] - s_xpos[t * 3 + 2];
    float dn = sqrtf(dx0 * dx0 + dx1 * dx1 + dx2 * dx2 + EPS * EPS);
    s_dxn[t] = make_float4(dx0, dx1, dx2, dn);
    s_inv[t] = 1.0f / (dn + EPS);
  }
  __syncthreads();

  float rbm = 0.f, rbb = 0.f;
  if (lane < K) { rbm = rbf_m[lane]; rbb = rbf_b[lane]; }

  // ---- edge phase: waves own contiguous 16-j ranges, two 64-j halves ----
  for (int half = 0; half < 2; ++half) {
    int jbase = half * 64 + w * 16;
    {  // sub-pass A: t1 rows (only wk live)
      float wk[52];
      #pragma unroll
      for (int k = 0; k < 50; ++k) wk[k] = eo1w[(128 + k) * F + lane];
      wk[50] = 0.f; wk[51] = 0.f;
      float w1d = eo1w[178 * F + lane];
      float nhk = (lane < K) ? hkB_in[(bN + jbase) * K + lane] : 0.f;
      float ne1 = e1B_in[(bN + jbase) * F + lane];
      for (int jj = 0; jj < 16; ++jj) {
        int j = jbase + jj;
        float hk = nhk, e1v = ne1;
        if (jj < 15) {
          nhk = (lane < K) ? hkB_in[(bN + j + 1) * K + lane] : 0.f;
          ne1 = e1B_in[(bN + j + 1) * F + lane];
        }
        float dn = s_dxn[j].w;
        if (lane < K) {
          float hkf = s_zkbase[lane] + hk;
          float e = __expf(-dn) - rbm;
          s_zk[w][lane] = __expf(-rbb * e * e) * hkf;
        }
        float ac0 = s_e1base[lane] + e1v + dn * w1d, ac1 = 0.f, ac2 = 0.f, ac3 = 0.f;
        const float4* z4 = (const float4*)(&s_zk[w][0]);
        #pragma unroll
        for (int k4 = 0; k4 < 13; ++k4) {
          float4 z = z4[k4];
          ac0 += z.x * wk[4 * k4];     ac1 += z.y * wk[4 * k4 + 1];
          ac2 += z.z * wk[4 * k4 + 2]; ac3 += z.w * wk[4 * k4 + 3];
        }
        t1buf[(j & 63) * 68 + lane] = silu_f((ac0 + ac1) + (ac2 + ac3));
      }
    }
    // same-wave rows -> no barrier needed
    {  // sub-pass B: he = t1 @ eo2 (only er live), b128-packed writes into he_T
      float er[64];
      #pragma unroll
      for (int r = 0; r < F; ++r) er[r] = eo2w[r * F + lane];
      float b2 = eo2b[lane];
      for (int jj4 = 0; jj4 < 4; ++jj4) {
        float hv[4];
        #pragma unroll
        for (int q = 0; q < 4; ++q) {
          int row = ((jbase + jj4 * 4 + q) & 63) * 68;
          const float4* t4 = (const float4*)(&t1buf[row]);
          float ac0 = b2, ac1 = 0.f, ac2 = 0.f, ac3 = 0.f;
          #pragma unroll
          for (int r4 = 0; r4 < 16; ++r4) {
            float4 tt = t4[r4];
            ac0 += tt.x * er[4 * r4];     ac1 += tt.y * er[4 * r4 + 1];
            ac2 += tt.z * er[4 * r4 + 2]; ac3 += tt.w * er[4 * r4 + 3];
          }
          hv[q] = (ac0 + ac1) + (ac2 + ac3);
        }
        *(float4*)(&s_heT[lane * 132 + jbase + jj4 * 4]) = make_float4(hv[0], hv[1], hv[2], hv[3]);
      }
    }
  }
  __syncthreads();  // he_T complete; t1buf dead -> union becomes scratch

  // ---- coeff phase: register-tiled 8j x 4c, 4 passes (32-reg acc tile, no spill) ----
  {
    int c0 = 4 * (t & 63);
    float4 aX = make_float4(0.f, 0.f, 0.f, 0.f);
    float4 aY = make_float4(0.f, 0.f, 0.f, 0.f);
    float4 aZ = make_float4(0.f, 0.f, 0.f, 0.f);
    #pragma unroll 1
    for (int p = 0; p < 4; ++p) {
      int j0 = w * 32 + p * 8;
      float4 cacc[8];
      #pragma unroll
      for (int jj = 0; jj < 8; ++jj) cacc[jj] = make_float4(0.f, 0.f, 0.f, 0.f);
      for (int r = 0; r < 64; ++r) {
        float4 xm4 = *(const float4*)(&xmix[r * C + c0]);
        const float4* hb = (const float4*)(&s_heT[r * 132 + j0]);
        float4 h0v = hb[0], h1v = hb[1];
#define CSTEP(idx, hval) \
        cacc[idx].x += (hval) * xm4.x; cacc[idx].y += (hval) * xm4.y; \
        cacc[idx].z += (hval) * xm4.z; cacc[idx].w += (hval) * xm4.w;
        CSTEP(0, h0v.x)  CSTEP(1, h0v.y)  CSTEP(2, h0v.z)  CSTEP(3, h0v.w)
        CSTEP(4, h1v.x)  CSTEP(5, h1v.y)  CSTEP(6, h1v.z)  CSTEP(7, h1v.w)
#undef CSTEP
      }
      #pragma unroll
      for (int jj = 0; jj < 8; ++jj) {
        int j = j0 + jj;
        float4 dq = s_dxn[j];
        float inv = s_inv[j];
        float s0 = tanh_f(cacc[jj].x) * inv;
        float s1 = tanh_f(cacc[jj].y) * inv;
        float s2 = tanh_f(cacc[jj].z) * inv;
        float s3 = tanh_f(cacc[jj].w) * inv;
        aX.x += dq.x * s0; aY.x += dq.y * s0; aZ.x += dq.z * s0;
        aX.y += dq.x * s1; aY.y += dq.y * s1; aZ.y += dq.z * s1;
        aX.z += dq.x * s2; aY.z += dq.y * s2; aZ.z += dq.z * s2;
        aX.w += dq.x * s3; aY.w += dq.y * s3; aZ.w += dq.z * s3;
      }
    }
    int cb = w * 768 + c0 * 3;
    s_cpart[cb + 0] = aX.x; s_cpart[cb + 1] = aY.x; s_cpart[cb + 2]  = aZ.x;
    s_cpart[cb + 3] = aX.y; s_cpart[cb + 4] = aY.y; s_cpart[cb + 5]  = aZ.y;
    s_cpart[cb + 6] = aX.z; s_cpart[cb + 7] = aY.z; s_cpart[cb + 8]  = aZ.z;
    s_cpart[cb + 9] = aX.w; s_cpart[cb + 10] = aY.w; s_cpart[cb + 11] = aZ.w;
  }

  // ---- attention phase: thread t -> j = t&127, heads {2g,2g+1}; he_T column reads ----
  {
    int g = t >> 7, j = t & 127;
    int ha = 2 * g, hb_ = ha + 1;
    float l0a = 0.f, l0b = 0.f, l1a = 0.f, l1b = 0.f;
    #pragma unroll 8
    for (int r = 0; r < 64; r += 2) {
      float hv0 = s_heT[r * 132 + j];
      float hv1 = s_heT[(r + 1) * 132 + j];
      l0a += hv0 * semw[r * H + ha];       l1a += hv0 * semw[r * H + hb_];
      l0b += hv1 * semw[(r + 1) * H + ha]; l1b += hv1 * semw[(r + 1) * H + hb_];
    }
    float l0 = semb[ha] + l0a + l0b;
    float l1 = semb[hb_] + l1a + l1b;
    l0 = l0 > 0.f ? l0 : 2.0f * (__expf(0.5f * l0) - 1.0f);  // celu alpha=2
    l1 = l1 > 0.f ? l1 : 2.0f * (__expf(0.5f * l1) - 1.0f);
    if (j == i) { l0 -= 1e5f; l1 -= 1e5f; }
    float m0 = l0, m1 = l1;
    #pragma unroll
    for (int off = 32; off > 0; off >>= 1) {
      m0 = fmaxf(m0, __shfl_xor(m0, off));
      m1 = fmaxf(m1, __shfl_xor(m1, off));
    }
    if (lane == 0) { s_wred[w * 2] = m0; s_wred[w * 2 + 1] = m1; }
    __syncthreads();   // also publishes s_cpart
    {  // hcin combine rides in this gap
      int c = t;
      float q0 = (s_cpart[c * 3 + 0] + s_cpart[768 + c * 3 + 0] + s_cpart[1536 + c * 3 + 0] + s_cpart[2304 + c * 3 + 0]) * invN;
      float q1 = (s_cpart[c * 3 + 1] + s_cpart[768 + c * 3 + 1] + s_cpart[1536 + c * 3 + 1] + s_cpart[2304 + c * 3 + 1]) * invN;
      float q2 = (s_cpart[c * 3 + 2] + s_cpart[768 + c * 3 + 2] + s_cpart[1536 + c * 3 + 2] + s_cpart[2304 + c * 3 + 2]) * invN;
      s_hcin[c] = q0 * q0 + q1 * q1 + q2 * q2;
    }
    int pw = w ^ 1;  // partner wave covers the other 64 j's of the same heads
    float M0 = fmaxf(s_wred[w * 2], s_wred[pw * 2]);
    float M1 = fmaxf(s_wred[w * 2 + 1], s_wred[pw * 2 + 1]);
    float e0 = __expf(l0 - M0), e1 = __expf(l1 - M1);
    float sm0 = e0, sm1 = e1;
    #pragma unroll
    for (int off = 32; off > 0; off >>= 1) {
      sm0 += __shfl_xor(sm0, off);
      sm1 += __shfl_xor(sm1, off);
    }
    if (lane == 0) { s_wsum[w * 2] = sm0; s_wsum[w * 2 + 1] = sm1; }
    __syncthreads();
    float S0 = s_wsum[w * 2] + s_wsum[pw * 2];
    float S1 = s_wsum[w * 2 + 1] + s_wsum[pw * 2 + 1];
    s_attT[ha * 128 + j] = e0 / S0;
    s_attT[hb_ * 128 + j] = e1 / S1;
  }
  __syncthreads();

  // ---- h_e phase: thread t -> (f = t>>2, head = t&3); j-contiguous b128 reads ----
  {
    int f = t >> 2, hh = t & 3;
    const float4* hr = (const float4*)(&s_heT[f * 132]);
    const float4* ar = (const float4*)(&s_attT[hh * 128]);
    float ac0 = 0.f, ac1 = 0.f, ac2 = 0.f, ac3 = 0.f;
    #pragma unroll 8
    for (int jg = 0; jg < 32; ++jg) {
      float4 hv = hr[jg];
      float4 av = ar[jg];
      ac0 += hv.x * av.x; ac1 += hv.y * av.y; ac2 += hv.z * av.z; ac3 += hv.w * av.w;
    }
    s_cat[64 + t] = (ac0 + ac1) + (ac2 + ac3);   // h_e slot of concat
  }

  // ---- node phase ----
  {
    int c0 = w * 64;
    float a0 = 0.f, a1 = 0.f, a2 = 0.f, a3 = 0.f;
    #pragma unroll 8
    for (int cc = 0; cc < 64; cc += 4) {
      a0 += s_hcin[c0 + cc] * p1w[(c0 + cc) * F + lane];
      a1 += s_hcin[c0 + cc + 1] * p1w[(c0 + cc + 1) * F + lane];
      a2 += s_hcin[c0 + cc + 2] * p1w[(c0 + cc + 2) * F + lane];
      a3 += s_hcin[c0 + cc + 3] * p1w[(c0 + cc + 3) * F + lane];
    }
    s_part[w * 64 + lane] = (a0 + a1) + (a2 + a3);
  }
  __syncthreads();
  if (t < F) s_vec[t] = silu_f(s_part[t] + s_part[64 + t] + s_part[128 + t] + s_part[192 + t] + p1b[t]);
  __syncthreads();
  if (t < F) {
    float a0 = p2b[t], a1 = 0.f, a2 = 0.f, a3 = 0.f;
    #pragma unroll 8
    for (int r = 0; r < F; r += 4) {
      a0 += s_vec[r] * p2w[r * F + t];
      a1 += s_vec[r + 1] * p2w[(r + 1) * F + t];
      a2 += s_vec[r + 2] * p2w[(r + 2) * F + t];
      a3 += s_vec[r + 3] * p2w[(r + 3) * F + t];
    }
    s_cat[t] = s_hi[t];
    s_cat[320 + t] = silu_f((a0 + a1) + (a2 + a3));
  }
  __syncthreads();
  {
    int r0 = w * 96;
    float a0 = 0.f, a1 = 0.f, a2 = 0.f, a3 = 0.f;
    #pragma unroll 8
    for (int rr = 0; rr < 96; rr += 4) {
      a0 += s_cat[r0 + rr] * n1w[(r0 + rr) * F + lane];
      a1 += s_cat[r0 + rr + 1] * n1w[(r0 + rr + 1) * F + lane];
      a2 += s_cat[r0 + rr + 2] * n1w[(r0 + rr + 2) * F + lane];
      a3 += s_cat[r0 + rr + 3] * n1w[(r0 + rr + 3) * F + lane];
    }
    s_part[w * 64 + lane] = (a0 + a1) + (a2 + a3);
  }
  __syncthreads();
  if (t < F) s_vec[t] = silu_f(s_part[t] + s_part[64 + t] + s_part[128 + t] + s_part[192 + t] + n1b[t]);
  __syncthreads();
  if (t < F) {
    float a0 = n2b[t], a1 = 0.f, a2 = 0.f, a3 = 0.f;
    #pragma unroll 8
    for (int r = 0; r < F; r += 4) {
      a0 += s_vec[r] * n2w[r * F + t];
      a1 += s_vec[r + 1] * n2w[(r + 1) * F + t];
      a2 += s_vec[r + 2] * n2w[(r + 2) * F + t];
      a3 += s_vec[r + 3] * n2w[(r + 3) * F + t];
    }
    float hn = s_hi[t] + silu_f((a0 + a1) + (a2 + a3));
    s_hnew[t] = hn;
    hw[(bN + i) * F + t] = hn;
  }
  __syncthreads();

  if (PRE) {  // next-step node precomp from updated h
    if (t < 228) {
      float a0 = 0.f, a1 = 0.f, a2 = 0.f, a3 = 0.f;
      if (t < 50) { int k = t;
        #pragma unroll
        for (int r = 0; r < F; r += 4) {
          a0 += s_hnew[r] * ein_w[r * K + k];       a1 += s_hnew[r + 1] * ein_w[(r + 1) * K + k];
          a2 += s_hnew[r + 2] * ein_w[(r + 2) * K + k]; a3 += s_hnew[r + 3] * ein_w[(r + 3) * K + k];
        }
        hkA_out[(bN + i) * K + k] = (a0 + a1) + (a2 + a3);
      } else if (t < 100) { int k = t - 50;
        #pragma unroll
        for (int r = 0; r < F; r += 4) {
          a0 += s_hnew[r] * ein_w[(F + r) * K + k];       a1 += s_hnew[r + 1] * ein_w[(F + r + 1) * K + k];
          a2 += s_hnew[r + 2] * ein_w[(F + r + 2) * K + k]; a3 += s_hnew[r + 3] * ein_w[(F + r + 3) * K + k];
        }
        hkB_out[(bN + i) * K + k] = (a0 + a1) + (a2 + a3);
      } else if (t < 164) { int c = t - 100;
        #pragma unroll
        for (int r = 0; r < F; r += 4) {
          a0 += s_hnew[r] * eo1w[r * F + c];       a1 += s_hnew[r + 1] * eo1w[(r + 1) * F + c];
          a2 += s_hnew[r + 2] * eo1w[(r + 2) * F + c]; a3 += s_hnew[r + 3] * eo1w[(r + 3) * F + c];
        }
        e1A_out[(bN + i) * F + c] = (a0 + a1) + (a2 + a3);
      } else { int c = t - 164;
        #pragma unroll
        for (int r = 0; r < F; r += 4) {
          a0 += s_hnew[r] * eo1w[(F + r) * F + c];       a1 += s_hnew[r + 1] * eo1w[(F + r + 1) * F + c];
          a2 += s_hnew[r + 2] * eo1w[(F + r + 2) * F + c]; a3 += s_hnew[r + 3] * eo1w[(F + r + 3) * F + c];
        }
        e1B_out[(bN + i) * F + c] = (a0 + a1) + (a2 + a3);
      }
    }
  }
  if (TAIL) {  // coord1 halves + vel scalar m for the flow tail
    if (w == 0) {
      float a0 = 0.f, a1 = 0.f, a2 = 0.f, a3 = 0.f;
      #pragma unroll
      for (int r = 0; r < F; r += 4) {
        a0 += s_hnew[r] * c1w[r * F + lane];       a1 += s_hnew[r + 1] * c1w[(r + 1) * F + lane];
        a2 += s_hnew[r + 2] * c1w[(r + 2) * F + lane]; a3 += s_hnew[r + 3] * c1w[(r + 3) * F + lane];
      }
      uA[(bN + i) * F + lane] = (a0 + a1) + (a2 + a3);
    } else if (w == 1) {
      float a0 = 0.f, a1 = 0.f, a2 = 0.f, a3 = 0.f;
      #pragma unroll
      for (int r = 0; r < F; r += 4) {
        a0 += s_hnew[r] * c1w[(F + r) * F + lane];       a1 += s_hnew[r + 1] * c1w[(F + r + 1) * F + lane];
        a2 += s_hnew[r + 2] * c1w[(F + r + 2) * F + lane]; a3 += s_hnew[r + 3] * c1w[(F + r + 3) * F + lane];
      }
      uB[(bN + i) * F + lane] = (a0 + a1) + (a2 + a3);
    } else if (w == 2) {
      float a0 = v1b[lane], a1 = 0.f, a2 = 0.f, a3 = 0.f;
      #pragma unroll
      for (int r = 0; r < F; r += 4) {
        a0 += s_hnew[r] * v1w[r * F + lane];       a1 += s_hnew[r + 1] * v1w[(r + 1) * F + lane];
        a2 += s_hnew[r + 2] * v1w[(r + 2) * F + lane]; a3 += s_hnew[r + 3] * v1w[(r + 3) * F + lane];
      }
      float tv = silu_f((a0 + a1) + (a2 + a3)) * v2w[lane];
      #pragma unroll
      for (int off = 32; off > 0; off >>= 1) tv += __shfl_down(tv, off);
      if (lane == 0) mbuf[bN + i] = tv;
    }
  }
}

// delta_v[b,i] = (1/N) sum_j (coord2 . silu(uA_i + uB_j + b)) * (x_i - x_j)
__global__ __launch_bounds__(256) void k_tail(const float* __restrict__ xb,
    const float* __restrict__ uA, const float* __restrict__ uB,
    const float* __restrict__ c1b, const float* __restrict__ c2w,
    float* __restrict__ dv) {
  int blk = blockIdx.x, b = blk >> 7, i = blk & 127;
  int t = threadIdx.x, w = t >> 6, lane = t & 63;
  __shared__ float s_xpos[N * 3];
  __shared__ float s_uAi[F];
  __shared__ float s_acc[4][3];
  for (int idx = t; idx < N * 3; idx += 256) s_xpos[idx] = xb[b * N * 3 + idx];
  if (t < F) s_uAi[t] = uA[(b * N + i) * F + t];
  __syncthreads();
  float xi0 = s_xpos[i * 3 + 0], xi1 = s_xpos[i * 3 + 1], xi2 = s_xpos[i * 3 + 2];
  float base = s_uAi[lane] + c1b[lane];
  float c2v = c2w[lane];
  float a0 = 0.f, a1 = 0.f, a2 = 0.f;
  for (int jj = 0; jj < 32; ++jj) {
    int j = w + 4 * jj;
    float tv = silu_f(base + uB[(b * N + j) * F + lane]) * c2v;
    #pragma unroll
    for (int off = 32; off > 0; off >>= 1) tv += __shfl_down(tv, off);
    if (lane == 0) {
      float dx0 = xi0 - s_xpos[j * 3 + 0];
      float dx1 = xi1 - s_xpos[j * 3 + 1];
      float dx2 = xi2 - s_xpos[j * 3 + 2];
      a0 += tv * dx0; a1 += tv * dx1; a2 += tv * dx2;
    }
  }
  if (lane == 0) { s_acc[w][0] = a0; s_acc[w][1] = a1; s_acc[w][2] = a2; }
  __syncthreads();
  if (t < 3) {
    float s = s_acc[0][t] + s_acc[1][t] + s_acc[2][t] + s_acc[3][t];
    dv[(b * N + i) * 3 + t] = s * (1.0f / (float)N);
  }
}

// apply v' = exp(m)*v + dv, x' = x + v'; center x and v; sld += 3*sum(m). One block per batch.
__global__ __launch_bounds__(128) void k_fin(float* __restrict__ xb, float* __restrict__ vb,
    const float* __restrict__ dv, const float* __restrict__ mbuf, float* __restrict__ sld) {
  int b = blockIdx.x, t = threadIdx.x;
  __shared__ float red[N];
  float m = mbuf[b * N + t];
  float em = __expf(m);
  float vv[3], xx[3];
  #pragma unroll
  for (int d = 0; d < 3; ++d) {
    int idx = (b * N + t) * 3 + d;
    vv[d] = em * vb[idx] + dv[idx];
    xx[d] = xb[idx] + vv[d];
  }
  #pragma unroll
  for (int d = 0; d < 3; ++d) {
    red[t] = xx[d];
    __syncthreads();
    for (int s = 64; s > 0; s >>= 1) { if (t < s) red[t] += red[t + s]; __syncthreads(); }
    xx[d] -= red[0] * (1.0f / (float)N);
    __syncthreads();
    red[t] = vv[d];
    __syncthreads();
    for (int s = 64; s > 0; s >>= 1) { if (t < s) red[t] += red[t + s]; __syncthreads(); }
    vv[d] -= red[0] * (1.0f / (float)N);
    __syncthreads();
  }
  #pragma unroll
  for (int d = 0; d < 3; ++d) {
    int idx = (b * N + t) * 3 + d;
    xb[idx] = xx[d];
    vb[idx] = vv[d];
  }
  red[t] = m;
  __syncthreads();
  for (int s = 64; s > 0; s >>= 1) { if (t < s) red[t] += red[t + s]; __syncthreads(); }
  if (t == 0) sld[b] += 3.0f * red[0];
}

__global__ void k_out(const float* __restrict__ xw, const float* __restrict__ vw,
                      const float* __restrict__ sld, float* __restrict__ out) {
  int t = blockIdx.x * blockDim.x + threadIdx.x;
  if (t < B * N * 3) { out[t] = xw[t]; out[B * N * 3 + t] = vw[t]; }
  if (t < B) out[2 * B * N * 3 + t] = sld[t];
}

}  // namespace

extern "C" void kernel_launch(void* const* d_in, const int* in_sizes, int n_in,
                              void* d_out, int out_size, void* d_ws, size_t ws_size,
                              hipStream_t stream) {
  const float* in_h   = (const float*)d_in[0];
  const float* in_x   = (const float*)d_in[1];
  const float* in_v   = (const float*)d_in[2];
  const float* emb1_w = (const float*)d_in[3];
  const float* emb1_b = (const float*)d_in[4];
  const float* emb2_w = (const float*)d_in[5];
  const float* emb2_b = (const float*)d_in[6];
  const float* ein_w  = (const float*)d_in[7];
  const float* ein_b  = (const float*)d_in[8];
  const float* rbf_m  = (const float*)d_in[9];
  const float* rbf_b  = (const float*)d_in[10];
  const float* eo1w   = (const float*)d_in[11];
  const float* eo1b   = (const float*)d_in[12];
  const float* eo2w   = (const float*)d_in[13];
  const float* eo2b   = (const float*)d_in[14];
  const float* xmix   = (const float*)d_in[15];
  const float* p1w    = (const float*)d_in[16];
  const float* p1b    = (const float*)d_in[17];
  const float* p2w    = (const float*)d_in[18];
  const float* p2b    = (const float*)d_in[19];
  const float* semw   = (const float*)d_in[20];
  const float* semb   = (const float*)d_in[21];
  const float* n1w    = (const float*)d_in[22];
  const float* n1b    = (const float*)d_in[23];
  const float* n2w    = (const float*)d_in[24];
  const float* n2b    = (const float*)d_in[25];
  const float* v1w    = (const float*)d_in[26];
  const float* v1b    = (const float*)d_in[27];
  const float* v2w    = (const float*)d_in[28];
  const float* c1w    = (const float*)d_in[29];
  const float* c1b    = (const float*)d_in[30];
  const float* c2w    = (const float*)d_in[31];

  float* ws   = (float*)d_ws;
  float* h0   = ws;                 // BN*F
  float* hw   = h0 + BN * F;        // BN*F
  float* hkA0 = hw + BN * F;        // BN*K
  float* hkB0 = hkA0 + BN * K;
  float* e1A0 = hkB0 + BN * K;      // BN*F
  float* e1B0 = e1A0 + BN * F;
  float* hkA1 = e1B0 + BN * F;
  float* hkB1 = hkA1 + BN * K;
  float* e1A1 = hkB1 + BN * K;
  float* e1B1 = e1A1 + BN * F;
  float* uA   = e1B1 + BN * F;      // BN*F
  float* uB   = uA + BN * F;
  float* xw   = uB + BN * F;        // BN*3
  float* vw   = xw + BN * 3;
  float* dvb  = vw + BN * 3;
  float* mbuf = dvb + BN * 3;       // BN
  float* sld  = mbuf + BN;          // B

  k_init<<<6, 256, 0, stream>>>(in_x, in_v, xw, vw, sld);
  k_embed<<<BN, F, 0, stream>>>(in_h, emb1_w, emb1_b, emb2_w, emb2_b, h0);

  float* hkA[2] = {hkA0, hkA1};
  float* hkB[2] = {hkB0, hkB1};
  float* e1A[2] = {e1A0, e1A1};
  float* e1B[2] = {e1B0, e1B1};

  for (int dep = 0; dep < 2; ++dep) {
    for (int half = 0; half < 2; ++half) {
      int l = 2 * dep + half;
      float* xb = half ? vw : xw;
      float* vb = half ? xw : vw;
      const float* einw_l = ein_w + l * 2 * F * K;
      const float* einb_l = ein_b + l * K;
      const float* rbm_l  = rbf_m + l * K;
      const float* rbb_l  = rbf_b + l * K;
      const float* eo1w_l = eo1w + l * 179 * F;
      const float* eo1b_l = eo1b + l * F;
      const float* eo2w_l = eo2w + l * F * F;
      const float* eo2b_l = eo2b + l * F;
      const float* xmix_l = xmix + l * F * C;
      const float* p1w_l  = p1w + l * C * F;
      const float* p1b_l  = p1b + l * F;
      const float* p2w_l  = p2w + l * F * F;
      const float* p2b_l  = p2b + l * F;
      const float* semw_l = semw + l * F * H;
      const float* semb_l = semb + l * H;
      const float* n1w_l  = n1w + l * 384 * F;
      const float* n1b_l  = n1b + l * F;
      const float* n2w_l  = n2w + l * F * F;
      const float* n2b_l  = n2b + l * F;
      const float* v1w_l  = v1w + l * F * F;
      const float* v1b_l  = v1b + l * F;
      const float* v2w_l  = v2w + l * F;
      const float* c1w_l  = c1w + l * 2 * F * F;
      const float* c1b_l  = c1b + l * F;
      const float* c2w_l  = c2w + l * F;

      k_pre<<<BN, 256, 0, stream>>>(h0, hw, einw_l, eo1w_l, hkA[0], hkB[0], e1A[0], e1B[0]);
      // step 0: in set0 -> out set1 ; step 1: in set1 -> out set0 ; step 2: in set0, tail
      k_mp<1, 0><<<BN, 256, 0, stream>>>(hw, xb, hkA[0], hkB[0], e1A[0], e1B[0],
          einb_l, rbm_l, rbb_l, eo1w_l, eo1b_l, eo2w_l, eo2b_l, xmix_l,
          p1w_l, p1b_l, p2w_l, p2b_l, semw_l, semb_l, n1w_l, n1b_l, n2w_l, n2b_l,
          einw_l, hkA[1], hkB[1], e1A[1], e1B[1],
          c1w_l, v1w_l, v1b_l, v2w_l, uA, uB, mbuf);
      k_mp<1, 0><<<BN, 256, 0, stream>>>(hw, xb, hkA[1], hkB[1], e1A[1], e1B[1],
          einb_l, rbm_l, rbb_l, eo1w_l, eo1b_l, eo2w_l, eo2b_l, xmix_l,
          p1w_l, p1b_l, p2w_l, p2b_l, semw_l, semb_l, n1w_l, n1b_l, n2w_l, n2b_l,
          einw_l, hkA[0], hkB[0], e1A[0], e1B[0],
          c1w_l, v1w_l, v1b_l, v2w_l, uA, uB, mbuf);
      k_mp<0, 1><<<BN, 256, 0, stream>>>(hw, xb, hkA[0], hkB[0], e1A[0], e1B[0],
          einb_l, rbm_l, rbb_l, eo1w_l, eo1b_l, eo2w_l, eo2b_l, xmix_l,
          p1w_l, p1b_l, p2w_l, p2b_l, semw_l, semb_l, n1w_l, n1b_l, n2w_l, n2b_l,
          einw_l, hkA[1], hkB[1], e1A[1], e1B[1],
          c1w_l, v1w_l, v1b_l, v2w_l, uA, uB, mbuf);
      k_tail<<<BN, 256, 0, stream>>>(xb, uA, uB, c1b_l, c2w_l, dvb);
      k_fin<<<B, 128, 0, stream>>>(xb, vb, dvb, mbuf, sld);
    }
  }
  k_out<<<6, 256, 0, stream>>>(xw, vw, sld, (float*)d_out);
}

// Round 5
// 1207.964 us; speedup vs baseline: 2.0508x; 1.0041x over previous
//
#include <hip/hip_runtime.h>
#include <math.h>

namespace {

constexpr int B = 4, N = 128, FIN = 16, F = 64, H = 4, K = 50, C = 256;
constexpr int BN = B * N;
constexpr float EPS = 1e-5f;

__device__ __forceinline__ float silu_f(float x) { return x / (1.0f + __expf(-x)); }
__device__ __forceinline__ float tanh_f(float x) { return 1.0f - 2.0f / (__expf(2.0f * x) + 1.0f); }

__global__ void k_init(const float* __restrict__ x, const float* __restrict__ v,
                       float* __restrict__ xw, float* __restrict__ vw, float* __restrict__ sld) {
  int t = blockIdx.x * blockDim.x + threadIdx.x;
  if (t < B * N * 3) { xw[t] = x[t]; vw[t] = v[t]; }
  if (t < B) sld[t] = 0.0f;
}

__global__ __launch_bounds__(F) void k_embed(const float* __restrict__ hin,
    const float* __restrict__ w1, const float* __restrict__ b1,
    const float* __restrict__ w2, const float* __restrict__ b2, float* __restrict__ h0) {
  int node = blockIdx.x, f = threadIdx.x;
  __shared__ float t1[F];
  float acc = b1[f];
  #pragma unroll
  for (int r = 0; r < FIN; ++r) acc += hin[node * FIN + r] * w1[r * F + f];
  t1[f] = silu_f(acc);
  __syncthreads();
  float a0 = b2[f], a1 = 0.f, a2 = 0.f, a3 = 0.f;
  #pragma unroll
  for (int r = 0; r < F; r += 4) {
    a0 += t1[r] * w2[r * F + f];
    a1 += t1[r + 1] * w2[(r + 1) * F + f];
    a2 += t1[r + 2] * w2[(r + 2) * F + f];
    a3 += t1[r + 3] * w2[(r + 3) * F + f];
  }
  h0[node * F + f] = (a0 + a1) + (a2 + a3);
}

// Per-node precomputation at flow start: hkA/hkB (edge_in halves), e1A/e1B (eo1 halves).
__global__ __launch_bounds__(256) void k_pre(const float* __restrict__ h0, float* __restrict__ hw,
    const float* __restrict__ ein_w, const float* __restrict__ eo1w,
    float* __restrict__ hkA, float* __restrict__ hkB,
    float* __restrict__ e1A, float* __restrict__ e1B) {
  int node = blockIdx.x, t = threadIdx.x;
  __shared__ float s_h[F];
  if (t < F) s_h[t] = h0[node * F + t];
  __syncthreads();
  if (t < F) hw[node * F + t] = s_h[t];
  if (t < 228) {
    float a0 = 0.f, a1 = 0.f, a2 = 0.f, a3 = 0.f;
    if (t < 50) { int k = t;
      #pragma unroll
      for (int r = 0; r < F; r += 4) {
        a0 += s_h[r] * ein_w[r * K + k];       a1 += s_h[r + 1] * ein_w[(r + 1) * K + k];
        a2 += s_h[r + 2] * ein_w[(r + 2) * K + k]; a3 += s_h[r + 3] * ein_w[(r + 3) * K + k];
      }
      hkA[node * K + k] = (a0 + a1) + (a2 + a3);
    } else if (t < 100) { int k = t - 50;
      #pragma unroll
      for (int r = 0; r < F; r += 4) {
        a0 += s_h[r] * ein_w[(F + r) * K + k];       a1 += s_h[r + 1] * ein_w[(F + r + 1) * K + k];
        a2 += s_h[r + 2] * ein_w[(F + r + 2) * K + k]; a3 += s_h[r + 3] * ein_w[(F + r + 3) * K + k];
      }
      hkB[node * K + k] = (a0 + a1) + (a2 + a3);
    } else if (t < 164) { int c = t - 100;
      #pragma unroll
      for (int r = 0; r < F; r += 4) {
        a0 += s_h[r] * eo1w[r * F + c];       a1 += s_h[r + 1] * eo1w[(r + 1) * F + c];
        a2 += s_h[r + 2] * eo1w[(r + 2) * F + c]; a3 += s_h[r + 3] * eo1w[(r + 3) * F + c];
      }
      e1A[node * F + c] = (a0 + a1) + (a2 + a3);
    } else { int c = t - 164;
      #pragma unroll
      for (int r = 0; r < F; r += 4) {
        a0 += s_h[r] * eo1w[(F + r) * F + c];       a1 += s_h[r + 1] * eo1w[(F + r + 1) * F + c];
        a2 += s_h[r + 2] * eo1w[(F + r + 2) * F + c]; a3 += s_h[r + 3] * eo1w[(F + r + 3) * F + c];
      }
      e1B[node * F + c] = (a0 + a1) + (a2 + a3);
    }
  }
}

// Fused message-passing step for one (b,i): 256 threads / 4 waves.
// amdgpu_waves_per_eu(2,2): grid is 512 blocks = 2 blocks/CU (grid-limited), so
// the allocator may use the full 256-VGPR budget -- eliminates the scratch spills
// the default 128-VGPR occupancy heuristic forced (WRITE_SIZE 66.7MB -> ~0.6MB).
// he stored TRANSPOSED (he_T[r][j], pad 132); coeff GEMM register-tiled 16j x 4c.
template<int PRE, int TAIL>
__global__ __attribute__((amdgpu_waves_per_eu(2, 2))) __launch_bounds__(256, 2) void k_mp(
    float* __restrict__ hw, const float* __restrict__ xp,
    const float* __restrict__ hkA_in, const float* __restrict__ hkB_in,
    const float* __restrict__ e1A_in, const float* __restrict__ e1B_in,
    const float* __restrict__ ein_b, const float* __restrict__ rbf_m, const float* __restrict__ rbf_b,
    const float* __restrict__ eo1w, const float* __restrict__ eo1b,
    const float* __restrict__ eo2w, const float* __restrict__ eo2b,
    const float* __restrict__ xmix,
    const float* __restrict__ p1w, const float* __restrict__ p1b,
    const float* __restrict__ p2w, const float* __restrict__ p2b,
    const float* __restrict__ semw, const float* __restrict__ semb,
    const float* __restrict__ n1w, const float* __restrict__ n1b,
    const float* __restrict__ n2w, const float* __restrict__ n2b,
    const float* __restrict__ ein_w,
    float* __restrict__ hkA_out, float* __restrict__ hkB_out,
    float* __restrict__ e1A_out, float* __restrict__ e1B_out,
    const float* __restrict__ c1w, const float* __restrict__ v1w, const float* __restrict__ v1b,
    const float* __restrict__ v2w,
    float* __restrict__ uA, float* __restrict__ uB, float* __restrict__ mbuf) {
  int blk = blockIdx.x, b = blk >> 7, i = blk & 127;
  int t = threadIdx.x, w = t >> 6, lane = t & 63;
  int bN = b * N;
  constexpr float invN = 1.0f / (float)N;

  __shared__ __align__(16) float s_heT[64 * 132];  // he transposed [r][j], pad 132
  __shared__ __align__(16) float s_union[4352];    // t1buf (edge) / post-edge scratch
  __shared__ __align__(16) float4 s_dxn[N];        // (dx0,dx1,dx2,dn)
  __shared__ float s_inv[N];                       // 1/(dn+EPS)
  __shared__ float s_xpos[N * 3];
  __shared__ float s_hi[F];
  __shared__ float s_zkbase[K];
  __shared__ float s_e1base[F];
  __shared__ __align__(16) float s_zk[4][56];
  __shared__ float s_cat[384];
  __shared__ float s_wred[8];
  __shared__ float s_wsum[8];

  float* t1buf   = s_union;          // [64][68]  (edge phase only)
  float* s_cpart = s_union;          // [4][256][3] = 3072 floats
  float* s_attT  = s_union + 3072;   // [4][128]
  float* s_hcin  = s_union + 3584;   // [256]
  float* s_part  = s_union + 3840;   // [4][64]
  float* s_vec   = s_union + 4096;   // [64]
  float* s_hnew  = s_union + 4160;   // [64]

  // ---- staging ----
  for (int idx = t; idx < N * 3; idx += 256) s_xpos[idx] = xp[bN * 3 + idx];
  if (t < F) s_hi[t] = hw[(bN + i) * F + t];
  if (t < K) s_zkbase[t] = hkA_in[(bN + i) * K + t] + ein_b[t];
  if (t >= 64 && t < 128) s_e1base[t - 64] = e1A_in[(bN + i) * F + (t - 64)] + eo1b[t - 64];
  if (lane >= 50 && lane < 56) s_zk[w][lane] = 0.f;  // float4 pad
  __syncthreads();
  if (t < N) {
    float dx0 = s_xpos[i * 3 + 0] - s_xpos[t * 3 + 0];
    float dx1 = s_xpos[i * 3 + 1] - s_xpos[t * 3 + 1];
    float dx2 = s_xpos[i * 3 + 2] - s_xpos[t * 3 + 2];
    float dn = sqrtf(dx0 * dx0 + dx1 * dx1 + dx2 * dx2 + EPS * EPS);
    s_dxn[t] = make_float4(dx0, dx1, dx2, dn);
    s_inv[t] = 1.0f / (dn + EPS);
  }
  __syncthreads();

  float rbm = 0.f, rbb = 0.f;
  if (lane < K) { rbm = rbf_m[lane]; rbb = rbf_b[lane]; }

  // ---- edge phase: waves own contiguous 16-j ranges, two 64-j halves ----
  for (int half = 0; half < 2; ++half) {
    int jbase = half * 64 + w * 16;
    {  // sub-pass A: t1 rows (only wk live)
      float wk[52];
      #pragma unroll
      for (int k = 0; k < 50; ++k) wk[k] = eo1w[(128 + k) * F + lane];
      wk[50] = 0.f; wk[51] = 0.f;
      float w1d = eo1w[178 * F + lane];
      float nhk = (lane < K) ? hkB_in[(bN + jbase) * K + lane] : 0.f;
      float ne1 = e1B_in[(bN + jbase) * F + lane];
      for (int jj = 0; jj < 16; ++jj) {
        int j = jbase + jj;
        float hk = nhk, e1v = ne1;
        if (jj < 15) {
          nhk = (lane < K) ? hkB_in[(bN + j + 1) * K + lane] : 0.f;
          ne1 = e1B_in[(bN + j + 1) * F + lane];
        }
        float dn = s_dxn[j].w;
        if (lane < K) {
          float hkf = s_zkbase[lane] + hk;
          float e = __expf(-dn) - rbm;
          s_zk[w][lane] = __expf(-rbb * e * e) * hkf;
        }
        float ac0 = s_e1base[lane] + e1v + dn * w1d, ac1 = 0.f, ac2 = 0.f, ac3 = 0.f;
        const float4* z4 = (const float4*)(&s_zk[w][0]);
        #pragma unroll
        for (int k4 = 0; k4 < 13; ++k4) {
          float4 z = z4[k4];
          ac0 += z.x * wk[4 * k4];     ac1 += z.y * wk[4 * k4 + 1];
          ac2 += z.z * wk[4 * k4 + 2]; ac3 += z.w * wk[4 * k4 + 3];
        }
        t1buf[(j & 63) * 68 + lane] = silu_f((ac0 + ac1) + (ac2 + ac3));
      }
    }
    // same-wave rows -> no barrier needed
    {  // sub-pass B: he = t1 @ eo2 (only er live), b128-packed writes into he_T
      float er[64];
      #pragma unroll
      for (int r = 0; r < F; ++r) er[r] = eo2w[r * F + lane];
      float b2 = eo2b[lane];
      for (int jj4 = 0; jj4 < 4; ++jj4) {
        float hv[4];
        #pragma unroll
        for (int q = 0; q < 4; ++q) {
          int row = ((jbase + jj4 * 4 + q) & 63) * 68;
          const float4* t4 = (const float4*)(&t1buf[row]);
          float ac0 = b2, ac1 = 0.f, ac2 = 0.f, ac3 = 0.f;
          #pragma unroll
          for (int r4 = 0; r4 < 16; ++r4) {
            float4 tt = t4[r4];
            ac0 += tt.x * er[4 * r4];     ac1 += tt.y * er[4 * r4 + 1];
            ac2 += tt.z * er[4 * r4 + 2]; ac3 += tt.w * er[4 * r4 + 3];
          }
          hv[q] = (ac0 + ac1) + (ac2 + ac3);
        }
        *(float4*)(&s_heT[lane * 132 + jbase + jj4 * 4]) = make_float4(hv[0], hv[1], hv[2], hv[3]);
      }
    }
  }
  __syncthreads();  // he_T complete; t1buf dead -> union becomes scratch

  // ---- coeff phase: register-tiled 16j x 4c, 2 passes (64-float acc tile) ----
  {
    int c0 = 4 * (t & 63);
    float4 aX = make_float4(0.f, 0.f, 0.f, 0.f);
    float4 aY = make_float4(0.f, 0.f, 0.f, 0.f);
    float4 aZ = make_float4(0.f, 0.f, 0.f, 0.f);
    #pragma unroll 1
    for (int p = 0; p < 2; ++p) {
      int j0 = w * 32 + p * 16;
      float4 cacc[16];
      #pragma unroll
      for (int jj = 0; jj < 16; ++jj) cacc[jj] = make_float4(0.f, 0.f, 0.f, 0.f);
      for (int r = 0; r < 64; ++r) {
        float4 xm4 = *(const float4*)(&xmix[r * C + c0]);
        const float4* hb = (const float4*)(&s_heT[r * 132 + j0]);
        float4 h0v = hb[0], h1v = hb[1], h2v = hb[2], h3v = hb[3];
#define CSTEP(idx, hval) \
        cacc[idx].x += (hval) * xm4.x; cacc[idx].y += (hval) * xm4.y; \
        cacc[idx].z += (hval) * xm4.z; cacc[idx].w += (hval) * xm4.w;
        CSTEP(0, h0v.x)  CSTEP(1, h0v.y)  CSTEP(2, h0v.z)  CSTEP(3, h0v.w)
        CSTEP(4, h1v.x)  CSTEP(5, h1v.y)  CSTEP(6, h1v.z)  CSTEP(7, h1v.w)
        CSTEP(8, h2v.x)  CSTEP(9, h2v.y)  CSTEP(10, h2v.z) CSTEP(11, h2v.w)
        CSTEP(12, h3v.x) CSTEP(13, h3v.y) CSTEP(14, h3v.z) CSTEP(15, h3v.w)
#undef CSTEP
      }
      #pragma unroll
      for (int jj = 0; jj < 16; ++jj) {
        int j = j0 + jj;
        float4 dq = s_dxn[j];
        float inv = s_inv[j];
        float s0 = tanh_f(cacc[jj].x) * inv;
        float s1 = tanh_f(cacc[jj].y) * inv;
        float s2 = tanh_f(cacc[jj].z) * inv;
        float s3 = tanh_f(cacc[jj].w) * inv;
        aX.x += dq.x * s0; aY.x += dq.y * s0; aZ.x += dq.z * s0;
        aX.y += dq.x * s1; aY.y += dq.y * s1; aZ.y += dq.z * s1;
        aX.z += dq.x * s2; aY.z += dq.y * s2; aZ.z += dq.z * s2;
        aX.w += dq.x * s3; aY.w += dq.y * s3; aZ.w += dq.z * s3;
      }
    }
    int cb = w * 768 + c0 * 3;
    s_cpart[cb + 0] = aX.x; s_cpart[cb + 1] = aY.x; s_cpart[cb + 2]  = aZ.x;
    s_cpart[cb + 3] = aX.y; s_cpart[cb + 4] = aY.y; s_cpart[cb + 5]  = aZ.y;
    s_cpart[cb + 6] = aX.z; s_cpart[cb + 7] = aY.z; s_cpart[cb + 8]  = aZ.z;
    s_cpart[cb + 9] = aX.w; s_cpart[cb + 10] = aY.w; s_cpart[cb + 11] = aZ.w;
  }

  // ---- attention phase: thread t -> j = t&127, heads {2g,2g+1}; he_T column reads ----
  {
    int g = t >> 7, j = t & 127;
    int ha = 2 * g, hb_ = ha + 1;
    float l0a = 0.f, l0b = 0.f, l1a = 0.f, l1b = 0.f;
    #pragma unroll 8
    for (int r = 0; r < 64; r += 2) {
      float hv0 = s_heT[r * 132 + j];
      float hv1 = s_heT[(r + 1) * 132 + j];
      l0a += hv0 * semw[r * H + ha];       l1a += hv0 * semw[r * H + hb_];
      l0b += hv1 * semw[(r + 1) * H + ha]; l1b += hv1 * semw[(r + 1) * H + hb_];
    }
    float l0 = semb[ha] + l0a + l0b;
    float l1 = semb[hb_] + l1a + l1b;
    l0 = l0 > 0.f ? l0 : 2.0f * (__expf(0.5f * l0) - 1.0f);  // celu alpha=2
    l1 = l1 > 0.f ? l1 : 2.0f * (__expf(0.5f * l1) - 1.0f);
    if (j == i) { l0 -= 1e5f; l1 -= 1e5f; }
    float m0 = l0, m1 = l1;
    #pragma unroll
    for (int off = 32; off > 0; off >>= 1) {
      m0 = fmaxf(m0, __shfl_xor(m0, off));
      m1 = fmaxf(m1, __shfl_xor(m1, off));
    }
    if (lane == 0) { s_wred[w * 2] = m0; s_wred[w * 2 + 1] = m1; }
    __syncthreads();   // also publishes s_cpart
    {  // hcin combine rides in this gap
      int c = t;
      float q0 = (s_cpart[c * 3 + 0] + s_cpart[768 + c * 3 + 0] + s_cpart[1536 + c * 3 + 0] + s_cpart[2304 + c * 3 + 0]) * invN;
      float q1 = (s_cpart[c * 3 + 1] + s_cpart[768 + c * 3 + 1] + s_cpart[1536 + c * 3 + 1] + s_cpart[2304 + c * 3 + 1]) * invN;
      float q2 = (s_cpart[c * 3 + 2] + s_cpart[768 + c * 3 + 2] + s_cpart[1536 + c * 3 + 2] + s_cpart[2304 + c * 3 + 2]) * invN;
      s_hcin[c] = q0 * q0 + q1 * q1 + q2 * q2;
    }
    int pw = w ^ 1;  // partner wave covers the other 64 j's of the same heads
    float M0 = fmaxf(s_wred[w * 2], s_wred[pw * 2]);
    float M1 = fmaxf(s_wred[w * 2 + 1], s_wred[pw * 2 + 1]);
    float e0 = __expf(l0 - M0), e1 = __expf(l1 - M1);
    float sm0 = e0, sm1 = e1;
    #pragma unroll
    for (int off = 32; off > 0; off >>= 1) {
      sm0 += __shfl_xor(sm0, off);
      sm1 += __shfl_xor(sm1, off);
    }
    if (lane == 0) { s_wsum[w * 2] = sm0; s_wsum[w * 2 + 1] = sm1; }
    __syncthreads();
    float S0 = s_wsum[w * 2] + s_wsum[pw * 2];
    float S1 = s_wsum[w * 2 + 1] + s_wsum[pw * 2 + 1];
    s_attT[ha * 128 + j] = e0 / S0;
    s_attT[hb_ * 128 + j] = e1 / S1;
  }
  __syncthreads();

  // ---- h_e phase: thread t -> (f = t>>2, head = t&3); j-contiguous b128 reads ----
  {
    int f = t >> 2, hh = t & 3;
    const float4* hr = (const float4*)(&s_heT[f * 132]);
    const float4* ar = (const float4*)(&s_attT[hh * 128]);
    float ac0 = 0.f, ac1 = 0.f, ac2 = 0.f, ac3 = 0.f;
    #pragma unroll 8
    for (int jg = 0; jg < 32; ++jg) {
      float4 hv = hr[jg];
      float4 av = ar[jg];
      ac0 += hv.x * av.x; ac1 += hv.y * av.y; ac2 += hv.z * av.z; ac3 += hv.w * av.w;
    }
    s_cat[64 + t] = (ac0 + ac1) + (ac2 + ac3);   // h_e slot of concat
  }

  // ---- node phase ----
  {
    int c0 = w * 64;
    float a0 = 0.f, a1 = 0.f, a2 = 0.f, a3 = 0.f;
    #pragma unroll 8
    for (int cc = 0; cc < 64; cc += 4) {
      a0 += s_hcin[c0 + cc] * p1w[(c0 + cc) * F + lane];
      a1 += s_hcin[c0 + cc + 1] * p1w[(c0 + cc + 1) * F + lane];
      a2 += s_hcin[c0 + cc + 2] * p1w[(c0 + cc + 2) * F + lane];
      a3 += s_hcin[c0 + cc + 3] * p1w[(c0 + cc + 3) * F + lane];
    }
    s_part[w * 64 + lane] = (a0 + a1) + (a2 + a3);
  }
  __syncthreads();
  if (t < F) s_vec[t] = silu_f(s_part[t] + s_part[64 + t] + s_part[128 + t] + s_part[192 + t] + p1b[t]);
  __syncthreads();
  if (t < F) {
    float a0 = p2b[t], a1 = 0.f, a2 = 0.f, a3 = 0.f;
    #pragma unroll 8
    for (int r = 0; r < F; r += 4) {
      a0 += s_vec[r] * p2w[r * F + t];
      a1 += s_vec[r + 1] * p2w[(r + 1) * F + t];
      a2 += s_vec[r + 2] * p2w[(r + 2) * F + t];
      a3 += s_vec[r + 3] * p2w[(r + 3) * F + t];
    }
    s_cat[t] = s_hi[t];
    s_cat[320 + t] = silu_f((a0 + a1) + (a2 + a3));
  }
  __syncthreads();
  {
    int r0 = w * 96;
    float a0 = 0.f, a1 = 0.f, a2 = 0.f, a3 = 0.f;
    #pragma unroll 8
    for (int rr = 0; rr < 96; rr += 4) {
      a0 += s_cat[r0 + rr] * n1w[(r0 + rr) * F + lane];
      a1 += s_cat[r0 + rr + 1] * n1w[(r0 + rr + 1) * F + lane];
      a2 += s_cat[r0 + rr + 2] * n1w[(r0 + rr + 2) * F + lane];
      a3 += s_cat[r0 + rr + 3] * n1w[(r0 + rr + 3) * F + lane];
    }
    s_part[w * 64 + lane] = (a0 + a1) + (a2 + a3);
  }
  __syncthreads();
  if (t < F) s_vec[t] = silu_f(s_part[t] + s_part[64 + t] + s_part[128 + t] + s_part[192 + t] + n1b[t]);
  __syncthreads();
  if (t < F) {
    float a0 = n2b[t], a1 = 0.f, a2 = 0.f, a3 = 0.f;
    #pragma unroll 8
    for (int r = 0; r < F; r += 4) {
      a0 += s_vec[r] * n2w[r * F + t];
      a1 += s_vec[r + 1] * n2w[(r + 1) * F + t];
      a2 += s_vec[r + 2] * n2w[(r + 2) * F + t];
      a3 += s_vec[r + 3] * n2w[(r + 3) * F + t];
    }
    float hn = s_hi[t] + silu_f((a0 + a1) + (a2 + a3));
    s_hnew[t] = hn;
    hw[(bN + i) * F + t] = hn;
  }
  __syncthreads();

  if (PRE) {  // next-step node precomp from updated h
    if (t < 228) {
      float a0 = 0.f, a1 = 0.f, a2 = 0.f, a3 = 0.f;
      if (t < 50) { int k = t;
        #pragma unroll
        for (int r = 0; r < F; r += 4) {
          a0 += s_hnew[r] * ein_w[r * K + k];       a1 += s_hnew[r + 1] * ein_w[(r + 1) * K + k];
          a2 += s_hnew[r + 2] * ein_w[(r + 2) * K + k]; a3 += s_hnew[r + 3] * ein_w[(r + 3) * K + k];
        }
        hkA_out[(bN + i) * K + k] = (a0 + a1) + (a2 + a3);
      } else if (t < 100) { int k = t - 50;
        #pragma unroll
        for (int r = 0; r < F; r += 4) {
          a0 += s_hnew[r] * ein_w[(F + r) * K + k];       a1 += s_hnew[r + 1] * ein_w[(F + r + 1) * K + k];
          a2 += s_hnew[r + 2] * ein_w[(F + r + 2) * K + k]; a3 += s_hnew[r + 3] * ein_w[(F + r + 3) * K + k];
        }
        hkB_out[(bN + i) * K + k] = (a0 + a1) + (a2 + a3);
      } else if (t < 164) { int c = t - 100;
        #pragma unroll
        for (int r = 0; r < F; r += 4) {
          a0 += s_hnew[r] * eo1w[r * F + c];       a1 += s_hnew[r + 1] * eo1w[(r + 1) * F + c];
          a2 += s_hnew[r + 2] * eo1w[(r + 2) * F + c]; a3 += s_hnew[r + 3] * eo1w[(r + 3) * F + c];
        }
        e1A_out[(bN + i) * F + c] = (a0 + a1) + (a2 + a3);
      } else { int c = t - 164;
        #pragma unroll
        for (int r = 0; r < F; r += 4) {
          a0 += s_hnew[r] * eo1w[(F + r) * F + c];       a1 += s_hnew[r + 1] * eo1w[(F + r + 1) * F + c];
          a2 += s_hnew[r + 2] * eo1w[(F + r + 2) * F + c]; a3 += s_hnew[r + 3] * eo1w[(F + r + 3) * F + c];
        }
        e1B_out[(bN + i) * F + c] = (a0 + a1) + (a2 + a3);
      }
    }
  }
  if (TAIL) {  // coord1 halves + vel scalar m for the flow tail
    if (w == 0) {
      float a0 = 0.f, a1 = 0.f, a2 = 0.f, a3 = 0.f;
      #pragma unroll
      for (int r = 0; r < F; r += 4) {
        a0 += s_hnew[r] * c1w[r * F + lane];       a1 += s_hnew[r + 1] * c1w[(r + 1) * F + lane];
        a2 += s_hnew[r + 2] * c1w[(r + 2) * F + lane]; a3 += s_hnew[r + 3] * c1w[(r + 3) * F + lane];
      }
      uA[(bN + i) * F + lane] = (a0 + a1) + (a2 + a3);
    } else if (w == 1) {
      float a0 = 0.f, a1 = 0.f, a2 = 0.f, a3 = 0.f;
      #pragma unroll
      for (int r = 0; r < F; r += 4) {
        a0 += s_hnew[r] * c1w[(F + r) * F + lane];       a1 += s_hnew[r + 1] * c1w[(F + r + 1) * F + lane];
        a2 += s_hnew[r + 2] * c1w[(F + r + 2) * F + lane]; a3 += s_hnew[r + 3] * c1w[(F + r + 3) * F + lane];
      }
      uB[(bN + i) * F + lane] = (a0 + a1) + (a2 + a3);
    } else if (w == 2) {
      float a0 = v1b[lane], a1 = 0.f, a2 = 0.f, a3 = 0.f;
      #pragma unroll
      for (int r = 0; r < F; r += 4) {
        a0 += s_hnew[r] * v1w[r * F + lane];       a1 += s_hnew[r + 1] * v1w[(r + 1) * F + lane];
        a2 += s_hnew[r + 2] * v1w[(r + 2) * F + lane]; a3 += s_hnew[r + 3] * v1w[(r + 3) * F + lane];
      }
      float tv = silu_f((a0 + a1) + (a2 + a3)) * v2w[lane];
      #pragma unroll
      for (int off = 32; off > 0; off >>= 1) tv += __shfl_down(tv, off);
      if (lane == 0) mbuf[bN + i] = tv;
    }
  }
}

// delta_v[b,i] = (1/N) sum_j (coord2 . silu(uA_i + uB_j + b)) * (x_i - x_j)
__global__ __launch_bounds__(256) void k_tail(const float* __restrict__ xb,
    const float* __restrict__ uA, const float* __restrict__ uB,
    const float* __restrict__ c1b, const float* __restrict__ c2w,
    float* __restrict__ dv) {
  int blk = blockIdx.x, b = blk >> 7, i = blk & 127;
  int t = threadIdx.x, w = t >> 6, lane = t & 63;
  __shared__ float s_xpos[N * 3];
  __shared__ float s_uAi[F];
  __shared__ float s_acc[4][3];
  for (int idx = t; idx < N * 3; idx += 256) s_xpos[idx] = xb[b * N * 3 + idx];
  if (t < F) s_uAi[t] = uA[(b * N + i) * F + t];
  __syncthreads();
  float xi0 = s_xpos[i * 3 + 0], xi1 = s_xpos[i * 3 + 1], xi2 = s_xpos[i * 3 + 2];
  float base = s_uAi[lane] + c1b[lane];
  float c2v = c2w[lane];
  float a0 = 0.f, a1 = 0.f, a2 = 0.f;
  for (int jj = 0; jj < 32; ++jj) {
    int j = w + 4 * jj;
    float tv = silu_f(base + uB[(b * N + j) * F + lane]) * c2v;
    #pragma unroll
    for (int off = 32; off > 0; off >>= 1) tv += __shfl_down(tv, off);
    if (lane == 0) {
      float dx0 = xi0 - s_xpos[j * 3 + 0];
      float dx1 = xi1 - s_xpos[j * 3 + 1];
      float dx2 = xi2 - s_xpos[j * 3 + 2];
      a0 += tv * dx0; a1 += tv * dx1; a2 += tv * dx2;
    }
  }
  if (lane == 0) { s_acc[w][0] = a0; s_acc[w][1] = a1; s_acc[w][2] = a2; }
  __syncthreads();
  if (t < 3) {
    float s = s_acc[0][t] + s_acc[1][t] + s_acc[2][t] + s_acc[3][t];
    dv[(b * N + i) * 3 + t] = s * (1.0f / (float)N);
  }
}

// apply v' = exp(m)*v + dv, x' = x + v'; center x and v; sld += 3*sum(m). One block per batch.
__global__ __launch_bounds__(128) void k_fin(float* __restrict__ xb, float* __restrict__ vb,
    const float* __restrict__ dv, const float* __restrict__ mbuf, float* __restrict__ sld) {
  int b = blockIdx.x, t = threadIdx.x;
  __shared__ float red[N];
  float m = mbuf[b * N + t];
  float em = __expf(m);
  float vv[3], xx[3];
  #pragma unroll
  for (int d = 0; d < 3; ++d) {
    int idx = (b * N + t) * 3 + d;
    vv[d] = em * vb[idx] + dv[idx];
    xx[d] = xb[idx] + vv[d];
  }
  #pragma unroll
  for (int d = 0; d < 3; ++d) {
    red[t] = xx[d];
    __syncthreads();
    for (int s = 64; s > 0; s >>= 1) { if (t < s) red[t] += red[t + s]; __syncthreads(); }
    xx[d] -= red[0] * (1.0f / (float)N);
    __syncthreads();
    red[t] = vv[d];
    __syncthreads();
    for (int s = 64; s > 0; s >>= 1) { if (t < s) red[t] += red[t + s]; __syncthreads(); }
    vv[d] -= red[0] * (1.0f / (float)N);
    __syncthreads();
  }
  #pragma unroll
  for (int d = 0; d < 3; ++d) {
    int idx = (b * N + t) * 3 + d;
    xb[idx] = xx[d];
    vb[idx] = vv[d];
  }
  red[t] = m;
  __syncthreads();
  for (int s = 64; s > 0; s >>= 1) { if (t < s) red[t] += red[t + s]; __syncthreads(); }
  if (t == 0) sld[b] += 3.0f * red[0];
}

__global__ void k_out(const float* __restrict__ xw, const float* __restrict__ vw,
                      const float* __restrict__ sld, float* __restrict__ out) {
  int t = blockIdx.x * blockDim.x + threadIdx.x;
  if (t < B * N * 3) { out[t] = xw[t]; out[B * N * 3 + t] = vw[t]; }
  if (t < B) out[2 * B * N * 3 + t] = sld[t];
}

}  // namespace

extern "C" void kernel_launch(void* const* d_in, const int* in_sizes, int n_in,
                              void* d_out, int out_size, void* d_ws, size_t ws_size,
                              hipStream_t stream) {
  const float* in_h   = (const float*)d_in[0];
  const float* in_x   = (const float*)d_in[1];
  const float* in_v   = (const float*)d_in[2];
  const float* emb1_w = (const float*)d_in[3];
  const float* emb1_b = (const float*)d_in[4];
  const float* emb2_w = (const float*)d_in[5];
  const float* emb2_b = (const float*)d_in[6];
  const float* ein_w  = (const float*)d_in[7];
  const float* ein_b  = (const float*)d_in[8];
  const float* rbf_m  = (const float*)d_in[9];
  const float* rbf_b  = (const float*)d_in[10];
  const float* eo1w   = (const float*)d_in[11];
  const float* eo1b   = (const float*)d_in[12];
  const float* eo2w   = (const float*)d_in[13];
  const float* eo2b   = (const float*)d_in[14];
  const float* xmix   = (const float*)d_in[15];
  const float* p1w    = (const float*)d_in[16];
  const float* p1b    = (const float*)d_in[17];
  const float* p2w    = (const float*)d_in[18];
  const float* p2b    = (const float*)d_in[19];
  const float* semw   = (const float*)d_in[20];
  const float* semb   = (const float*)d_in[21];
  const float* n1w    = (const float*)d_in[22];
  const float* n1b    = (const float*)d_in[23];
  const float* n2w    = (const float*)d_in[24];
  const float* n2b    = (const float*)d_in[25];
  const float* v1w    = (const float*)d_in[26];
  const float* v1b    = (const float*)d_in[27];
  const float* v2w    = (const float*)d_in[28];
  const float* c1w    = (const float*)d_in[29];
  const float* c1b    = (const float*)d_in[30];
  const float* c2w    = (const float*)d_in[31];

  float* ws   = (float*)d_ws;
  float* h0   = ws;                 // BN*F
  float* hw   = h0 + BN * F;        // BN*F
  float* hkA0 = hw + BN * F;        // BN*K
  float* hkB0 = hkA0 + BN * K;
  float* e1A0 = hkB0 + BN * K;      // BN*F
  float* e1B0 = e1A0 + BN * F;
  float* hkA1 = e1B0 + BN * F;
  float* hkB1 = hkA1 + BN * K;
  float* e1A1 = hkB1 + BN * K;
  float* e1B1 = e1A1 + BN * F;
  float* uA   = e1B1 + BN * F;      // BN*F
  float* uB   = uA + BN * F;
  float* xw   = uB + BN * F;        // BN*3
  float* vw   = xw + BN * 3;
  float* dvb  = vw + BN * 3;
  float* mbuf = dvb + BN * 3;       // BN
  float* sld  = mbuf + BN;          // B

  k_init<<<6, 256, 0, stream>>>(in_x, in_v, xw, vw, sld);
  k_embed<<<BN, F, 0, stream>>>(in_h, emb1_w, emb1_b, emb2_w, emb2_b, h0);

  float* hkA[2] = {hkA0, hkA1};
  float* hkB[2] = {hkB0, hkB1};
  float* e1A[2] = {e1A0, e1A1};
  float* e1B[2] = {e1B0, e1B1};

  for (int dep = 0; dep < 2; ++dep) {
    for (int half = 0; half < 2; ++half) {
      int l = 2 * dep + half;
      float* xb = half ? vw : xw;
      float* vb = half ? xw : vw;
      const float* einw_l = ein_w + l * 2 * F * K;
      const float* einb_l = ein_b + l * K;
      const float* rbm_l  = rbf_m + l * K;
      const float* rbb_l  = rbf_b + l * K;
      const float* eo1w_l = eo1w + l * 179 * F;
      const float* eo1b_l = eo1b + l * F;
      const float* eo2w_l = eo2w + l * F * F;
      const float* eo2b_l = eo2b + l * F;
      const float* xmix_l = xmix + l * F * C;
      const float* p1w_l  = p1w + l * C * F;
      const float* p1b_l  = p1b + l * F;
      const float* p2w_l  = p2w + l * F * F;
      const float* p2b_l  = p2b + l * F;
      const float* semw_l = semw + l * F * H;
      const float* semb_l = semb + l * H;
      const float* n1w_l  = n1w + l * 384 * F;
      const float* n1b_l  = n1b + l * F;
      const float* n2w_l  = n2w + l * F * F;
      const float* n2b_l  = n2b + l * F;
      const float* v1w_l  = v1w + l * F * F;
      const float* v1b_l  = v1b + l * F;
      const float* v2w_l  = v2w + l * F;
      const float* c1w_l  = c1w + l * 2 * F * F;
      const float* c1b_l  = c1b + l * F;
      const float* c2w_l  = c2w + l * F;

      k_pre<<<BN, 256, 0, stream>>>(h0, hw, einw_l, eo1w_l, hkA[0], hkB[0], e1A[0], e1B[0]);
      // step 0: in set0 -> out set1 ; step 1: in set1 -> out set0 ; step 2: in set0, tail
      k_mp<1, 0><<<BN, 256, 0, stream>>>(hw, xb, hkA[0], hkB[0], e1A[0], e1B[0],
          einb_l, rbm_l, rbb_l, eo1w_l, eo1b_l, eo2w_l, eo2b_l, xmix_l,
          p1w_l, p1b_l, p2w_l, p2b_l, semw_l, semb_l, n1w_l, n1b_l, n2w_l, n2b_l,
          einw_l, hkA[1], hkB[1], e1A[1], e1B[1],
          c1w_l, v1w_l, v1b_l, v2w_l, uA, uB, mbuf);
      k_mp<1, 0><<<BN, 256, 0, stream>>>(hw, xb, hkA[1], hkB[1], e1A[1], e1B[1],
          einb_l, rbm_l, rbb_l, eo1w_l, eo1b_l, eo2w_l, eo2b_l, xmix_l,
          p1w_l, p1b_l, p2w_l, p2b_l, semw_l, semb_l, n1w_l, n1b_l, n2w_l, n2b_l,
          einw_l, hkA[0], hkB[0], e1A[0], e1B[0],
          c1w_l, v1w_l, v1b_l, v2w_l, uA, uB, mbuf);
      k_mp<0, 1><<<BN, 256, 0, stream>>>(hw, xb, hkA[0], hkB[0], e1A[0], e1B[0],
          einb_l, rbm_l, rbb_l, eo1w_l, eo1b_l, eo2w_l, eo2b_l, xmix_l,
          p1w_l, p1b_l, p2w_l, p2b_l, semw_l, semb_l, n1w_l, n1b_l, n2w_l, n2b_l,
          einw_l, hkA[1], hkB[1], e1A[1], e1B[1],
          c1w_l, v1w_l, v1b_l, v2w_l, uA, uB, mbuf);
      k_tail<<<BN, 256, 0, stream>>>(xb, uA, uB, c1b_l, c2w_l, dvb);
      k_fin<<<B, 128, 0, stream>>>(xb, vb, dvb, mbuf, sld);
    }
  }
  k_out<<<6, 256, 0, stream>>>(xw, vw, sld, (float*)d_out);
}